// Round 5
// baseline (399.703 us; speedup 1.0000x reference)
//
#include <hip/hip_runtime.h>

#define D 128
#define NH 8

typedef __bf16 bf16x8 __attribute__((ext_vector_type(8)));
typedef unsigned short ushortx8 __attribute__((ext_vector_type(8)));
typedef float floatx4 __attribute__((ext_vector_type(4)));

__device__ __forceinline__ float bf2f(unsigned short u) {
  union { unsigned int i; float f; } x; x.i = ((unsigned int)u) << 16; return x.f;
}
__device__ __forceinline__ unsigned short f2bf(float f) {
  union { float f; unsigned int i; } x; x.f = f;
  unsigned int i = x.i;
  return (unsigned short)((i + 0x7FFFu + ((i >> 16) & 1u)) >> 16);
}
__device__ __forceinline__ void acc2(unsigned int ku, unsigned int qu, float& s) {
  union { unsigned int i; float f; } a, b;
  a.i = ku << 16;          b.i = qu << 16;          s += a.f * b.f;
  a.i = ku & 0xffff0000u;  b.i = qu & 0xffff0000u;  s += a.f * b.f;
}

// =============== phase helpers (proven bodies) ==============================
// weight fold: p0 Wk ; p1 Wq.rel_attT * pri*2.5 ; p2..4 Wq.wm_mT ; p5 Wv.rel_msg
__device__ __forceinline__ void fold_item(
    int gid,
    const float* __restrict__ Wk, const float* __restrict__ bk,
    const float* __restrict__ Wq, const float* __restrict__ bq,
    const float* __restrict__ Wv, const float* __restrict__ bv,
    const float* __restrict__ rel_att, const float* __restrict__ rel_msg,
    const float* __restrict__ rel_pri,
    const float* __restrict__ wm0, const float* __restrict__ wm1,
    const float* __restrict__ wm2,
    unsigned short* __restrict__ Wt_all, float* __restrict__ bias_all)
{
  int p = gid >> 14;
  int idx = gid & 16383;
  int c = idx >> 7, k = idx & 127;
  int h = c >> 4, r = c & 15;
  float wsum = 0.f, bsum = 0.f;
  if (p == 0) {
    wsum = Wk[k * 128 + c];
    bsum = bk[c];
  } else if (p <= 4) {
    const float* M = (p == 1) ? rel_att : ((p == 2) ? wm0 : ((p == 3) ? wm1 : wm2));
#pragma unroll
    for (int f = 0; f < 16; f++) {
      float mv = M[h * 256 + r * 16 + f];
      wsum += Wq[k * 128 + h * 16 + f] * mv;
      bsum += bq[h * 16 + f] * mv;
    }
    if (p == 1) { float sc = rel_pri[h] * 2.5f; wsum *= sc; bsum *= sc; }
  } else {
#pragma unroll
    for (int d = 0; d < 16; d++) {
      float mv = rel_msg[h * 256 + d * 16 + r];
      wsum += Wv[k * 128 + h * 16 + d] * mv;
      bsum += bv[h * 16 + d] * mv;
    }
  }
  Wt_all[(size_t)p * 16384 + c * 128 + k] = f2bf(wsum);
  if (k == 0) bias_all[p * 128 + c] = bsum;
}

// one 64-row x 4-plane projection tile, 256 threads.
// Weight panel staged in TWO 64-column halves (17.4KB LDS); each half's
// accumulators finished before the next half starts (4 live floatx4).
__device__ __forceinline__ void proj_tile(
    int t, const float* __restrict__ x0, const float* __restrict__ x1,
    const float* __restrict__ x2,
    const unsigned short* __restrict__ Wt_all, const float* __restrict__ bias_all,
    unsigned short* __restrict__ P, int N, unsigned short* Wt, int tid)
{
  int m = t % 3, rt = t / 3;
  const float* X = (m == 0) ? x0 : ((m == 1) ? x1 : x2);
  int wave = tid >> 6, lane = tid & 63;
  int quad = lane >> 4, l16 = lane & 15;
  int row0 = rt * 64 + wave * 16;
  int arow = row0 + l16; if (arow >= N) arow = N - 1;
  const float* ap = X + (size_t)arow * D;
  bf16x8 afr[4];
#pragma unroll
  for (int kk4 = 0; kk4 < 4; kk4++) {
    float4 f0 = *(const float4*)(ap + kk4 * 32 + quad * 8);
    float4 f1 = *(const float4*)(ap + kk4 * 32 + quad * 8 + 4);
    ushortx8 uu;
    uu[0]=f2bf(f0.x); uu[1]=f2bf(f0.y); uu[2]=f2bf(f0.z); uu[3]=f2bf(f0.w);
    uu[4]=f2bf(f1.x); uu[5]=f2bf(f1.y); uu[6]=f2bf(f1.z); uu[7]=f2bf(f1.w);
    afr[kk4] = __builtin_bit_cast(bf16x8, uu);
  }
  for (int pt = 0; pt < 4; pt++) {
    int wp = (pt == 0) ? 0 : ((pt == 1) ? 1 : ((pt == 2) ? (2 + m) : 5));
    const unsigned short* Wsrc = Wt_all + (size_t)wp * 16384;
    const float* B = bias_all + wp * 128;
    unsigned short* Pout = P + (size_t)(pt * 3 + m) * N * D;
    for (int half = 0; half < 2; half++) {
      __syncthreads();
#pragma unroll
      for (int it = 0; it < 4; it++) {
        int idx = it * 256 + tid;            // 0..1023
        int c = idx >> 4, kc = (idx & 15) << 3;
        *(uint4*)(&Wt[c * 136 + kc]) =
            *(const uint4*)(&Wsrc[(half * 64 + c) * 128 + kc]);
      }
      __syncthreads();
      floatx4 acc[4];
#pragma unroll
      for (int ct = 0; ct < 4; ct++) acc[ct] = (floatx4)0.f;
#pragma unroll
      for (int kk4 = 0; kk4 < 4; kk4++) {
#pragma unroll
        for (int ct2 = 0; ct2 < 4; ct2++) {
          uint4 bu = *(const uint4*)(&Wt[(ct2 * 16 + l16) * 136 + kk4 * 32 + quad * 8]);
          bf16x8 bf = __builtin_bit_cast(bf16x8, bu);
          acc[ct2] =
              __builtin_amdgcn_mfma_f32_16x16x32_bf16(afr[kk4], bf, acc[ct2], 0, 0, 0);
        }
      }
#pragma unroll
      for (int ct2 = 0; ct2 < 4; ct2++) {
        int col = half * 64 + ct2 * 16 + l16;
        float bias = B[col];
#pragma unroll
        for (int i = 0; i < 4; i++) {
          int r = row0 + quad * 4 + i;
          if (r < N) Pout[(size_t)r * D + col] = f2bf(acc[ct2][i] + bias);
        }
      }
    }
  }
}

// unordered CSR segment assignment: one wave handles 64 nodes, one atomicAdd
__device__ __forceinline__ void assign_chunk(
    int a, const int* __restrict__ counts, int* __restrict__ row_start,
    int* __restrict__ cursor, int* __restrict__ allocg, int N, int lane)
{
  int n = a * 64 + lane;
  int cnt = (n < N) ? counts[n] : 0;
  int x = cnt;
#pragma unroll
  for (int off = 1; off < 64; off <<= 1) {
    int y = __shfl_up(x, off, 64);
    if (lane >= off) x += y;
  }
  int wtot = __shfl(x, 63, 64);
  int wbase = 0;
  if (lane == 63) wbase = atomicAdd(allocg, wtot);
  wbase = __shfl(wbase, 63, 64);
  if (n < N) { int v = wbase + x - cnt; row_start[n] = v; cursor[n] = v; }
}

// one dst node per wave — round-8 body verbatim (register q-caches; the
// LDS/min-waves variant spilled to scratch: 86us vs 63us — keep registers).
__device__ __forceinline__ void edge_vals(
    const unsigned short* __restrict__ P, size_t Nsz, int s, int h,
    const uint4 (&qa)[3][2], const uint4 (&qw)[3][2],
    float (&av)[3], float (&lv)[3])
{
#pragma unroll
  for (int m = 0; m < 3; m++) {
    const unsigned short* kp = P + ((size_t)m * Nsz + s) * 128 + h * 16;
    uint4 k0 = *(const uint4*)kp, k1 = *(const uint4*)(kp + 8);
    const unsigned int* ka = (const unsigned int*)&k0;
    const unsigned int* kb = (const unsigned int*)&k1;
    const unsigned int* a0 = (const unsigned int*)&qa[m][0];
    const unsigned int* a1 = (const unsigned int*)&qa[m][1];
    const unsigned int* w0 = (const unsigned int*)&qw[m][0];
    const unsigned int* w1 = (const unsigned int*)&qw[m][1];
    float da = 0.f, dw = 0.f;
#pragma unroll
    for (int j = 0; j < 4; j++) {
      acc2(ka[j], a0[j], da); acc2(kb[j], a1[j], da);
      acc2(ka[j], w0[j], dw); acc2(kb[j], w1[j], dw);
    }
    av[m] = da;
    lv[m] = dw;
  }
  float mx = fmaxf(lv[0], fmaxf(lv[1], lv[2]));
  float e0 = __expf(lv[0] - mx), e1 = __expf(lv[1] - mx), e2 = __expf(lv[2] - mx);
  float inv = 1.f / (e0 + e1 + e2);
  lv[0] = e0 * inv; lv[1] = e1 * inv; lv[2] = e2 * inv;
}

__device__ __forceinline__ void node_one(
    int n, const unsigned short* __restrict__ P,
    const int* __restrict__ row_start, const int* __restrict__ counts,
    const int* __restrict__ srcs, unsigned short* __restrict__ hagg,
    int N, int lane)
{
  int ro = row_start[n];
  int deg = counts[n];
  float acc00 = 0, acc01 = 0, acc10 = 0, acc11 = 0, acc20 = 0, acc21 = 0;
  if (deg > 0) {
    int h = lane & 7, slot = lane >> 3;
    size_t Nsz = (size_t)N;
    uint4 qa[3][2], qw[3][2];
#pragma unroll
    for (int m = 0; m < 3; m++) {
      const unsigned short* qap = P + ((size_t)(3 + m) * Nsz + n) * 128 + h * 16;
      const unsigned short* qwp = P + ((size_t)(6 + m) * Nsz + n) * 128 + h * 16;
      qa[m][0] = *(const uint4*)qap; qa[m][1] = *(const uint4*)(qap + 8);
      qw[m][0] = *(const uint4*)qwp; qw[m][1] = *(const uint4*)(qwp + 8);
    }
    int nch = (deg + 7) >> 3;
    float cX0[4] = {}, cX1[4] = {}, cX2[4] = {}, cEa[4] = {}, cT[4] = {};
    int cS[4] = {};
    float sA0 = 0, sA1 = 0, sA2 = 0, sAl = 0;
#pragma unroll
    for (int c = 0; c < 4; c++) {
      int idx = c * 8 + slot;
      if (c < nch && idx < deg) {
        int s = srcs[ro + idx]; cS[c] = s;
        float av[3], lv[3];
        edge_vals(P, Nsz, s, h, qa, qw, av, lv);
        float e0 = __expf(av[0]), e1 = __expf(av[1]), e2 = __expf(av[2]);
        float align = -(fabsf(av[0]-av[1]) + fabsf(av[0]-av[2]) + fabsf(av[1]-av[2])) * (1.f/3.f);
        float ea = __expf(align);
        cX0[c] = lv[0] * e0; cX1[c] = lv[1] * e1; cX2[c] = lv[2] * e2; cEa[c] = ea;
        sA0 += e0; sA1 += e1; sA2 += e2; sAl += ea;
      }
    }
    for (int c = 4; c < nch; c++) {
      int idx = c * 8 + slot;
      if (idx < deg) {
        int s = srcs[ro + idx];
        float av[3], lv[3];
        edge_vals(P, Nsz, s, h, qa, qw, av, lv);
        float align = -(fabsf(av[0]-av[1]) + fabsf(av[0]-av[2]) + fabsf(av[1]-av[2])) * (1.f/3.f);
        sA0 += __expf(av[0]); sA1 += __expf(av[1]); sA2 += __expf(av[2]);
        sAl += __expf(align);
      }
    }
#pragma unroll
    for (int off = 8; off < 64; off <<= 1) {
      sA0 += __shfl_xor(sA0, off, 64);
      sA1 += __shfl_xor(sA1, off, 64);
      sA2 += __shfl_xor(sA2, off, 64);
      sAl += __shfl_xor(sAl, off, 64);
    }
    float rA0 = 1.f / fmaxf(sA0, 1e-30f), rA1 = 1.f / fmaxf(sA1, 1e-30f);
    float rA2 = 1.f / fmaxf(sA2, 1e-30f), rAl = 1.f / fmaxf(sAl, 1e-30f);
    float sT = 0;
#pragma unroll
    for (int c = 0; c < 4; c++) {
      int idx = c * 8 + slot;
      if (c < nch && idx < deg) {
        float t = (cX0[c] * rA0 + cX1[c] * rA1 + cX2[c] * rA2) * (cEa[c] * rAl);
        cT[c] = t;
        sT += __expf(t);
      }
    }
    for (int c = 4; c < nch; c++) {
      int idx = c * 8 + slot;
      if (idx < deg) {
        int s = srcs[ro + idx];
        float av[3], lv[3];
        edge_vals(P, Nsz, s, h, qa, qw, av, lv);
        float align = -(fabsf(av[0]-av[1]) + fabsf(av[0]-av[2]) + fabsf(av[1]-av[2])) * (1.f/3.f);
        float t = (lv[0]*__expf(av[0])*rA0 + lv[1]*__expf(av[1])*rA1 + lv[2]*__expf(av[2])*rA2)
                  * (__expf(align) * rAl);
        sT += __expf(t);
      }
    }
#pragma unroll
    for (int off = 8; off < 64; off <<= 1) sT += __shfl_xor(sT, off, 64);
    float rT = 1.f / fmaxf(sT, 1e-30f);
    const unsigned int* Pu = (const unsigned int*)P;
    int hl = lane >> 3;
#pragma unroll
    for (int c = 0; c < 4; c++) {
      if (c < nch) {
        int idx = c * 8 + slot;
        float beta = (idx < deg) ? __expf(cT[c]) * rT : 0.f;
        int sv = cS[c];
        float bj[8]; int sj[8];
#pragma unroll
        for (int jj = 0; jj < 8; jj++) {
          bj[jj] = __shfl(beta, jj * 8 + hl, 64);
          sj[jj] = __shfl(sv, jj * 8, 64);
        }
#pragma unroll
        for (int jj = 0; jj < 8; jj++) {
          size_t base9 = ((size_t)9 * Nsz + sj[jj]) * 64 + lane;
          unsigned int u0 = Pu[base9];
          unsigned int u1 = Pu[base9 + Nsz * 64];
          unsigned int u2 = Pu[base9 + 2 * Nsz * 64];
          float b = bj[jj];
          acc00 += b * bf2f((unsigned short)u0); acc01 += b * bf2f((unsigned short)(u0 >> 16));
          acc10 += b * bf2f((unsigned short)u1); acc11 += b * bf2f((unsigned short)(u1 >> 16));
          acc20 += b * bf2f((unsigned short)u2); acc21 += b * bf2f((unsigned short)(u2 >> 16));
        }
      }
    }
    for (int c = 4; c < nch; c++) {
      int idx = c * 8 + slot;
      float beta = 0.f; int sv = 0;
      if (idx < deg) {
        sv = srcs[ro + idx];
        float av[3], lv[3];
        edge_vals(P, Nsz, sv, h, qa, qw, av, lv);
        float align = -(fabsf(av[0]-av[1]) + fabsf(av[0]-av[2]) + fabsf(av[1]-av[2])) * (1.f/3.f);
        float t = (lv[0]*__expf(av[0])*rA0 + lv[1]*__expf(av[1])*rA1 + lv[2]*__expf(av[2])*rA2)
                  * (__expf(align) * rAl);
        beta = __expf(t) * rT;
      }
      int jmax = min(8, deg - c * 8);
      for (int jj = 0; jj < jmax; jj++) {
        float b = __shfl(beta, jj * 8 + hl, 64);
        int s = __shfl(sv, jj * 8, 64);
        size_t base9 = ((size_t)9 * Nsz + s) * 64 + lane;
        unsigned int u0 = Pu[base9];
        unsigned int u1 = Pu[base9 + Nsz * 64];
        unsigned int u2 = Pu[base9 + 2 * Nsz * 64];
        acc00 += b * bf2f((unsigned short)u0); acc01 += b * bf2f((unsigned short)(u0 >> 16));
        acc10 += b * bf2f((unsigned short)u1); acc11 += b * bf2f((unsigned short)(u1 >> 16));
        acc20 += b * bf2f((unsigned short)u2); acc21 += b * bf2f((unsigned short)(u2 >> 16));
      }
    }
  }
  unsigned int* ho = (unsigned int*)hagg;
  ho[((size_t)0 * N + n) * 64 + lane] = ((unsigned int)f2bf(acc01) << 16) | f2bf(acc00);
  ho[((size_t)1 * N + n) * 64 + lane] = ((unsigned int)f2bf(acc11) << 16) | f2bf(acc10);
  ho[((size_t)2 * N + n) * 64 + lane] = ((unsigned int)f2bf(acc21) << 16) | f2bf(acc20);
}

// one 64-row output tile for ONE 64-column half; Wa half pre-staged in Wt
__device__ __forceinline__ void out_tile_half(
    int t, int half, const unsigned short* __restrict__ Hagg,
    const float* __restrict__ ba,
    const float* __restrict__ x0, const float* __restrict__ x1,
    const float* __restrict__ x2, float alpha,
    float* __restrict__ out, int N, const unsigned short* Wt, int tid)
{
  int m = t % 3, rt = t / 3;
  const float* X = (m == 0) ? x0 : ((m == 1) ? x1 : x2);
  float oma = 1.f - alpha;
  int wave = tid >> 6, lane = tid & 63;
  int quad = lane >> 4, l16 = lane & 15;
  int row0 = rt * 64 + wave * 16;
  int arow = row0 + l16; if (arow >= N) arow = N - 1;
  const unsigned short* hp = Hagg + ((size_t)m * N + arow) * D;
  floatx4 acc[4];
#pragma unroll
  for (int ct = 0; ct < 4; ct++) acc[ct] = (floatx4)0.f;
#pragma unroll
  for (int kk = 0; kk < 128; kk += 32) {
    uint4 au = *(const uint4*)(hp + kk + quad * 8);
    bf16x8 af = __builtin_bit_cast(bf16x8, au);
#pragma unroll
    for (int ct = 0; ct < 4; ct++) {
      uint4 bu = *(const uint4*)(&Wt[(ct * 16 + l16) * 136 + kk + quad * 8]);
      bf16x8 bf = __builtin_bit_cast(bf16x8, bu);
      acc[ct] = __builtin_amdgcn_mfma_f32_16x16x32_bf16(af, bf, acc[ct], 0, 0, 0);
    }
  }
  float* om = out + (size_t)m * N * D;
#pragma unroll
  for (int ct = 0; ct < 4; ct++) {
    int col = half * 64 + ct * 16 + l16;
    float bias = ba[col];
#pragma unroll
    for (int i = 0; i < 4; i++) {
      int r = row0 + quad * 4 + i;
      if (r < N) {
        om[(size_t)r * D + col] =
            (acc[ct][i] + bias) * alpha + X[(size_t)r * D + col] * oma;
      }
    }
  }
}

// =============== multi-kernel path (primary) ================================
__global__ __launch_bounds__(256) void fb_misc(
    const float* Wk, const float* bk, const float* Wq, const float* bq,
    const float* Wv, const float* bv,
    const float* rel_att, const float* rel_msg, const float* rel_pri,
    const float* wm0, const float* wm1, const float* wm2,
    unsigned short* Wt_all, float* bias_all,
    const int* dst, int* counts, int E)
{
  int b = blockIdx.x;
  if (b < 384) {
    int g = b * 256 + threadIdx.x;
    if (g < 6 * 16384)
      fold_item(g, Wk, bk, Wq, bq, Wv, bv, rel_att, rel_msg, rel_pri,
                wm0, wm1, wm2, Wt_all, bias_all);
  } else {
    int e = (b - 384) * 256 + threadIdx.x;
    if (e < E) atomicAdd(&counts[dst[e]], 1);
  }
}

__global__ __launch_bounds__(256) void fb_projassign(
    const float* x0, const float* x1, const float* x2,
    const unsigned short* Wt_all, const float* bias_all,
    unsigned short* P, const int* counts, int* row_start, int* cursor,
    int* allocg, int N)
{
  __shared__ __attribute__((aligned(16))) unsigned short Wt[64 * 136];
  int ntiles = ((N + 63) / 64) * 3;
  int b = blockIdx.x;
  if (b < ntiles) {
    proj_tile(b, x0, x1, x2, Wt_all, bias_all, P, N, Wt, threadIdx.x);
  } else {
    int a = (b - ntiles) * 4 + (threadIdx.x >> 6);
    if (a < (N + 63) / 64)
      assign_chunk(a, counts, row_start, cursor, allocg, N, threadIdx.x & 63);
  }
}

__global__ void fb_scatter(const int* dst, const int* src, int* cursor,
                           int* src_sorted, int E) {
  int e = blockIdx.x * 256 + threadIdx.x;
  if (e < E) {
    int d = dst[e];
    int pos = atomicAdd(&cursor[d], 1);
    src_sorted[pos] = src[e];
  }
}

// fb_node: 1024-thread blocks (16 waves = 4 waves/SIMD, forced residency).
// r4 evidence: at 256-thread blocks the HW kept only ~1.3 blocks/CU resident
// (OccupancyPercent 16.5% ~= 5.3 waves/CU) despite VGPR=112 permitting 4
// waves/SIMD; VALU 40% + HBM 27% -> latency-bound with idle wave slots.
// A single 16-wave block is hosted atomically -> 16 waves/CU guaranteed.
// Codegen-safe: launch_bounds(1024) caps VGPR at 128 > natural 112 (no
// squeeze — unlike r2/r3's below-watermark caps which spilled/regressed).
__global__ __launch_bounds__(1024) void fb_node(
    const unsigned short* P, const int* row_start, const int* counts,
    const int* srcs, unsigned short* hagg, int N)
{
  int n = blockIdx.x * 16 + (threadIdx.x >> 6);
  if (n < N) node_one(n, P, row_start, counts, srcs, hagg, N, threadIdx.x & 63);
}

__global__ __launch_bounds__(256) void fb_out(
    const unsigned short* Hagg, const float* Wa, const float* ba,
    const float* x0, const float* x1, const float* x2, const float* skip,
    float* out, int N)
{
  __shared__ __attribute__((aligned(16))) unsigned short Wt[64 * 136];
  int tid = threadIdx.x;
  float alpha = 1.f / (1.f + __expf(-skip[0]));
  for (int half = 0; half < 2; half++) {
    __syncthreads();
#pragma unroll
    for (int it = 0; it < 8; it++) {
      int idx = it * 256 + tid;
      int k = idx >> 4;
      int c4 = (idx & 15) << 2;
      float4 w = *(const float4*)(&Wa[k * 128 + half * 64 + c4]);
      Wt[(c4 + 0) * 136 + k] = f2bf(w.x);
      Wt[(c4 + 1) * 136 + k] = f2bf(w.y);
      Wt[(c4 + 2) * 136 + k] = f2bf(w.z);
      Wt[(c4 + 3) * 136 + k] = f2bf(w.w);
    }
    __syncthreads();
    out_tile_half(blockIdx.x, half, Hagg, ba, x0, x1, x2, alpha, out, N, Wt, tid);
  }
}

// ---------------------------------------------------------------- launch
extern "C" void kernel_launch(void* const* d_in, const int* in_sizes, int n_in,
                              void* d_out, int out_size, void* d_ws, size_t ws_size,
                              hipStream_t stream) {
  const float* x0 = (const float*)d_in[0];
  const float* x1 = (const float*)d_in[1];
  const float* x2 = (const float*)d_in[2];
  const float* Wk = (const float*)d_in[3];
  const float* bk = (const float*)d_in[4];
  const float* Wq = (const float*)d_in[5];
  const float* bq = (const float*)d_in[6];
  const float* Wv = (const float*)d_in[7];
  const float* bv = (const float*)d_in[8];
  const float* Wa = (const float*)d_in[9];
  const float* ba = (const float*)d_in[10];
  const float* rel_att = (const float*)d_in[11];
  const float* rel_msg = (const float*)d_in[12];
  const float* rel_pri = (const float*)d_in[13];
  const float* wm0 = (const float*)d_in[14];
  const float* wm1 = (const float*)d_in[15];
  const float* wm2 = (const float*)d_in[16];
  const float* skip = (const float*)d_in[17];
  const int* src = (const int*)d_in[18];
  const int* dstv = (const int*)d_in[19];
  int N = in_sizes[0] / D;      // 20000
  int E = in_sizes[18];         // 160000

  char* wsb = (char*)d_ws;
  size_t off = 0;
  auto alloc_b = [&](size_t bytes) { size_t o = off; off += (bytes + 63) & ~(size_t)63; return o; };
  unsigned short* P         = (unsigned short*)(wsb + alloc_b((size_t)12 * N * D * 2));
  unsigned short* Wt_all    = (unsigned short*)(wsb + alloc_b((size_t)6 * 16384 * 2));
  float*          bias_all  = (float*)(wsb + alloc_b((size_t)6 * 128 * 4));
  // ctrl: bar[8*16] | alloc[16] | counts[N] | cursor[N]
  int*            ctrl      = (int*)(wsb + alloc_b(((size_t)144 + 2 * N) * 4));
  int*            row_start = (int*)(wsb + alloc_b((size_t)(N + 1) * 4));
  int*            src_sorted= (int*)(wsb + alloc_b((size_t)E * 4));
  unsigned short* hagg      = (unsigned short*)(wsb + alloc_b((size_t)3 * N * D * 2));
  int* allocg = ctrl + 128;
  int* counts = ctrl + 144;
  int* cursor = ctrl + 144 + N;

  // zero alloc + counts (cursor written by assign phase)
  hipMemsetAsync(ctrl, 0, ((size_t)144 + N) * sizeof(int), stream);

  int ntiles = ((N + 63) / 64) * 3;
  int nchunks = (N + 63) / 64;
  fb_misc<<<dim3(384 + (E + 255) / 256), 256, 0, stream>>>(
      Wk, bk, Wq, bq, Wv, bv, rel_att, rel_msg, rel_pri, wm0, wm1, wm2,
      Wt_all, bias_all, dstv, counts, E);
  fb_projassign<<<dim3(ntiles + (nchunks + 3) / 4), 256, 0, stream>>>(
      x0, x1, x2, Wt_all, bias_all, P, counts, row_start, cursor, allocg, N);
  fb_scatter<<<dim3((E + 255) / 256), 256, 0, stream>>>(
      dstv, src, cursor, src_sorted, E);
  fb_node<<<dim3((N + 15) / 16), 1024, 0, stream>>>(
      P, row_start, counts, src_sorted, hagg, N);
  fb_out<<<dim3(ntiles), 256, 0, stream>>>(
      hagg, Wa, ba, x0, x1, x2, skip, (float*)d_out, N);
}

// Round 6
// 255.032 us; speedup vs baseline: 1.5673x; 1.5673x over previous
//
#include <hip/hip_runtime.h>

#define D 128
#define NH 8

typedef __bf16 bf16x8 __attribute__((ext_vector_type(8)));
typedef unsigned short ushortx8 __attribute__((ext_vector_type(8)));
typedef float floatx4 __attribute__((ext_vector_type(4)));

__device__ __forceinline__ float bf2f(unsigned short u) {
  union { unsigned int i; float f; } x; x.i = ((unsigned int)u) << 16; return x.f;
}
__device__ __forceinline__ unsigned short f2bf(float f) {
  union { float f; unsigned int i; } x; x.f = f;
  unsigned int i = x.i;
  return (unsigned short)((i + 0x7FFFu + ((i >> 16) & 1u)) >> 16);
}
__device__ __forceinline__ void acc2(unsigned int ku, unsigned int qu, float& s) {
  union { unsigned int i; float f; } a, b;
  a.i = ku << 16;          b.i = qu << 16;          s += a.f * b.f;
  a.i = ku & 0xffff0000u;  b.i = qu & 0xffff0000u;  s += a.f * b.f;
}

// =============== phase helpers (proven bodies) ==============================
// weight fold: p0 Wk ; p1 Wq.rel_attT * pri*2.5 ; p2..4 Wq.wm_mT ; p5 Wv.rel_msg
__device__ __forceinline__ void fold_item(
    int gid,
    const float* __restrict__ Wk, const float* __restrict__ bk,
    const float* __restrict__ Wq, const float* __restrict__ bq,
    const float* __restrict__ Wv, const float* __restrict__ bv,
    const float* __restrict__ rel_att, const float* __restrict__ rel_msg,
    const float* __restrict__ rel_pri,
    const float* __restrict__ wm0, const float* __restrict__ wm1,
    const float* __restrict__ wm2,
    unsigned short* __restrict__ Wt_all, float* __restrict__ bias_all)
{
  int p = gid >> 14;
  int idx = gid & 16383;
  int c = idx >> 7, k = idx & 127;
  int h = c >> 4, r = c & 15;
  float wsum = 0.f, bsum = 0.f;
  if (p == 0) {
    wsum = Wk[k * 128 + c];
    bsum = bk[c];
  } else if (p <= 4) {
    const float* M = (p == 1) ? rel_att : ((p == 2) ? wm0 : ((p == 3) ? wm1 : wm2));
#pragma unroll
    for (int f = 0; f < 16; f++) {
      float mv = M[h * 256 + r * 16 + f];
      wsum += Wq[k * 128 + h * 16 + f] * mv;
      bsum += bq[h * 16 + f] * mv;
    }
    if (p == 1) { float sc = rel_pri[h] * 2.5f; wsum *= sc; bsum *= sc; }
  } else {
#pragma unroll
    for (int d = 0; d < 16; d++) {
      float mv = rel_msg[h * 256 + d * 16 + r];
      wsum += Wv[k * 128 + h * 16 + d] * mv;
      bsum += bv[h * 16 + d] * mv;
    }
  }
  Wt_all[(size_t)p * 16384 + c * 128 + k] = f2bf(wsum);
  if (k == 0) bias_all[p * 128 + c] = bsum;
}

// one 64-row x 4-plane projection tile, 256 threads.
// Weight panel staged in TWO 64-column halves (17.4KB LDS); each half's
// accumulators finished before the next half starts (4 live floatx4).
__device__ __forceinline__ void proj_tile(
    int t, const float* __restrict__ x0, const float* __restrict__ x1,
    const float* __restrict__ x2,
    const unsigned short* __restrict__ Wt_all, const float* __restrict__ bias_all,
    unsigned short* __restrict__ P, int N, unsigned short* Wt, int tid)
{
  int m = t % 3, rt = t / 3;
  const float* X = (m == 0) ? x0 : ((m == 1) ? x1 : x2);
  int wave = tid >> 6, lane = tid & 63;
  int quad = lane >> 4, l16 = lane & 15;
  int row0 = rt * 64 + wave * 16;
  int arow = row0 + l16; if (arow >= N) arow = N - 1;
  const float* ap = X + (size_t)arow * D;
  bf16x8 afr[4];
#pragma unroll
  for (int kk4 = 0; kk4 < 4; kk4++) {
    float4 f0 = *(const float4*)(ap + kk4 * 32 + quad * 8);
    float4 f1 = *(const float4*)(ap + kk4 * 32 + quad * 8 + 4);
    ushortx8 uu;
    uu[0]=f2bf(f0.x); uu[1]=f2bf(f0.y); uu[2]=f2bf(f0.z); uu[3]=f2bf(f0.w);
    uu[4]=f2bf(f1.x); uu[5]=f2bf(f1.y); uu[6]=f2bf(f1.z); uu[7]=f2bf(f1.w);
    afr[kk4] = __builtin_bit_cast(bf16x8, uu);
  }
  for (int pt = 0; pt < 4; pt++) {
    int wp = (pt == 0) ? 0 : ((pt == 1) ? 1 : ((pt == 2) ? (2 + m) : 5));
    const unsigned short* Wsrc = Wt_all + (size_t)wp * 16384;
    const float* B = bias_all + wp * 128;
    unsigned short* Pout = P + (size_t)(pt * 3 + m) * N * D;
    for (int half = 0; half < 2; half++) {
      __syncthreads();
#pragma unroll
      for (int it = 0; it < 4; it++) {
        int idx = it * 256 + tid;            // 0..1023
        int c = idx >> 4, kc = (idx & 15) << 3;
        *(uint4*)(&Wt[c * 136 + kc]) =
            *(const uint4*)(&Wsrc[(half * 64 + c) * 128 + kc]);
      }
      __syncthreads();
      floatx4 acc[4];
#pragma unroll
      for (int ct = 0; ct < 4; ct++) acc[ct] = (floatx4)0.f;
#pragma unroll
      for (int kk4 = 0; kk4 < 4; kk4++) {
#pragma unroll
        for (int ct2 = 0; ct2 < 4; ct2++) {
          uint4 bu = *(const uint4*)(&Wt[(ct2 * 16 + l16) * 136 + kk4 * 32 + quad * 8]);
          bf16x8 bf = __builtin_bit_cast(bf16x8, bu);
          acc[ct2] =
              __builtin_amdgcn_mfma_f32_16x16x32_bf16(afr[kk4], bf, acc[ct2], 0, 0, 0);
        }
      }
#pragma unroll
      for (int ct2 = 0; ct2 < 4; ct2++) {
        int col = half * 64 + ct2 * 16 + l16;
        float bias = B[col];
#pragma unroll
        for (int i = 0; i < 4; i++) {
          int r = row0 + quad * 4 + i;
          if (r < N) Pout[(size_t)r * D + col] = f2bf(acc[ct2][i] + bias);
        }
      }
    }
  }
}

// unordered CSR segment assignment: one wave handles 64 nodes, one atomicAdd
__device__ __forceinline__ void assign_chunk(
    int a, const int* __restrict__ counts, int* __restrict__ row_start,
    int* __restrict__ cursor, int* __restrict__ allocg, int N, int lane)
{
  int n = a * 64 + lane;
  int cnt = (n < N) ? counts[n] : 0;
  int x = cnt;
#pragma unroll
  for (int off = 1; off < 64; off <<= 1) {
    int y = __shfl_up(x, off, 64);
    if (lane >= off) x += y;
  }
  int wtot = __shfl(x, 63, 64);
  int wbase = 0;
  if (lane == 63) wbase = atomicAdd(allocg, wtot);
  wbase = __shfl(wbase, 63, 64);
  if (n < N) { int v = wbase + x - cnt; row_start[n] = v; cursor[n] = v; }
}

// one dst node per wave — round-8 body verbatim (register q-caches; the
// LDS/min-waves variant spilled to scratch: 86us vs 63us — keep registers).
__device__ __forceinline__ void edge_vals(
    const unsigned short* __restrict__ P, size_t Nsz, int s, int h,
    const uint4 (&qa)[3][2], const uint4 (&qw)[3][2],
    float (&av)[3], float (&lv)[3])
{
#pragma unroll
  for (int m = 0; m < 3; m++) {
    const unsigned short* kp = P + ((size_t)m * Nsz + s) * 128 + h * 16;
    uint4 k0 = *(const uint4*)kp, k1 = *(const uint4*)(kp + 8);
    const unsigned int* ka = (const unsigned int*)&k0;
    const unsigned int* kb = (const unsigned int*)&k1;
    const unsigned int* a0 = (const unsigned int*)&qa[m][0];
    const unsigned int* a1 = (const unsigned int*)&qa[m][1];
    const unsigned int* w0 = (const unsigned int*)&qw[m][0];
    const unsigned int* w1 = (const unsigned int*)&qw[m][1];
    float da = 0.f, dw = 0.f;
#pragma unroll
    for (int j = 0; j < 4; j++) {
      acc2(ka[j], a0[j], da); acc2(kb[j], a1[j], da);
      acc2(ka[j], w0[j], dw); acc2(kb[j], w1[j], dw);
    }
    av[m] = da;
    lv[m] = dw;
  }
  float mx = fmaxf(lv[0], fmaxf(lv[1], lv[2]));
  float e0 = __expf(lv[0] - mx), e1 = __expf(lv[1] - mx), e2 = __expf(lv[2] - mx);
  float inv = 1.f / (e0 + e1 + e2);
  lv[0] = e0 * inv; lv[1] = e1 * inv; lv[2] = e2 * inv;
}

__device__ __forceinline__ void node_one(
    int n, const unsigned short* __restrict__ P,
    const int* __restrict__ row_start, const int* __restrict__ counts,
    const int* __restrict__ srcs, unsigned short* __restrict__ hagg,
    int N, int lane)
{
  int ro = row_start[n];
  int deg = counts[n];
  float acc00 = 0, acc01 = 0, acc10 = 0, acc11 = 0, acc20 = 0, acc21 = 0;
  if (deg > 0) {
    int h = lane & 7, slot = lane >> 3;
    size_t Nsz = (size_t)N;
    uint4 qa[3][2], qw[3][2];
#pragma unroll
    for (int m = 0; m < 3; m++) {
      const unsigned short* qap = P + ((size_t)(3 + m) * Nsz + n) * 128 + h * 16;
      const unsigned short* qwp = P + ((size_t)(6 + m) * Nsz + n) * 128 + h * 16;
      qa[m][0] = *(const uint4*)qap; qa[m][1] = *(const uint4*)(qap + 8);
      qw[m][0] = *(const uint4*)qwp; qw[m][1] = *(const uint4*)(qwp + 8);
    }
    int nch = (deg + 7) >> 3;
    float cX0[4] = {}, cX1[4] = {}, cX2[4] = {}, cEa[4] = {}, cT[4] = {};
    int cS[4] = {};
    float sA0 = 0, sA1 = 0, sA2 = 0, sAl = 0;
#pragma unroll
    for (int c = 0; c < 4; c++) {
      int idx = c * 8 + slot;
      if (c < nch && idx < deg) {
        int s = srcs[ro + idx]; cS[c] = s;
        float av[3], lv[3];
        edge_vals(P, Nsz, s, h, qa, qw, av, lv);
        float e0 = __expf(av[0]), e1 = __expf(av[1]), e2 = __expf(av[2]);
        float align = -(fabsf(av[0]-av[1]) + fabsf(av[0]-av[2]) + fabsf(av[1]-av[2])) * (1.f/3.f);
        float ea = __expf(align);
        cX0[c] = lv[0] * e0; cX1[c] = lv[1] * e1; cX2[c] = lv[2] * e2; cEa[c] = ea;
        sA0 += e0; sA1 += e1; sA2 += e2; sAl += ea;
      }
    }
    for (int c = 4; c < nch; c++) {
      int idx = c * 8 + slot;
      if (idx < deg) {
        int s = srcs[ro + idx];
        float av[3], lv[3];
        edge_vals(P, Nsz, s, h, qa, qw, av, lv);
        float align = -(fabsf(av[0]-av[1]) + fabsf(av[0]-av[2]) + fabsf(av[1]-av[2])) * (1.f/3.f);
        sA0 += __expf(av[0]); sA1 += __expf(av[1]); sA2 += __expf(av[2]);
        sAl += __expf(align);
      }
    }
#pragma unroll
    for (int off = 8; off < 64; off <<= 1) {
      sA0 += __shfl_xor(sA0, off, 64);
      sA1 += __shfl_xor(sA1, off, 64);
      sA2 += __shfl_xor(sA2, off, 64);
      sAl += __shfl_xor(sAl, off, 64);
    }
    float rA0 = 1.f / fmaxf(sA0, 1e-30f), rA1 = 1.f / fmaxf(sA1, 1e-30f);
    float rA2 = 1.f / fmaxf(sA2, 1e-30f), rAl = 1.f / fmaxf(sAl, 1e-30f);
    float sT = 0;
#pragma unroll
    for (int c = 0; c < 4; c++) {
      int idx = c * 8 + slot;
      if (c < nch && idx < deg) {
        float t = (cX0[c] * rA0 + cX1[c] * rA1 + cX2[c] * rA2) * (cEa[c] * rAl);
        cT[c] = t;
        sT += __expf(t);
      }
    }
    for (int c = 4; c < nch; c++) {
      int idx = c * 8 + slot;
      if (idx < deg) {
        int s = srcs[ro + idx];
        float av[3], lv[3];
        edge_vals(P, Nsz, s, h, qa, qw, av, lv);
        float align = -(fabsf(av[0]-av[1]) + fabsf(av[0]-av[2]) + fabsf(av[1]-av[2])) * (1.f/3.f);
        float t = (lv[0]*__expf(av[0])*rA0 + lv[1]*__expf(av[1])*rA1 + lv[2]*__expf(av[2])*rA2)
                  * (__expf(align) * rAl);
        sT += __expf(t);
      }
    }
#pragma unroll
    for (int off = 8; off < 64; off <<= 1) sT += __shfl_xor(sT, off, 64);
    float rT = 1.f / fmaxf(sT, 1e-30f);
    const unsigned int* Pu = (const unsigned int*)P;
    int hl = lane >> 3;
#pragma unroll
    for (int c = 0; c < 4; c++) {
      if (c < nch) {
        int idx = c * 8 + slot;
        float beta = (idx < deg) ? __expf(cT[c]) * rT : 0.f;
        int sv = cS[c];
        float bj[8]; int sj[8];
#pragma unroll
        for (int jj = 0; jj < 8; jj++) {
          bj[jj] = __shfl(beta, jj * 8 + hl, 64);
          sj[jj] = __shfl(sv, jj * 8, 64);
        }
#pragma unroll
        for (int jj = 0; jj < 8; jj++) {
          size_t base9 = ((size_t)9 * Nsz + sj[jj]) * 64 + lane;
          unsigned int u0 = Pu[base9];
          unsigned int u1 = Pu[base9 + Nsz * 64];
          unsigned int u2 = Pu[base9 + 2 * Nsz * 64];
          float b = bj[jj];
          acc00 += b * bf2f((unsigned short)u0); acc01 += b * bf2f((unsigned short)(u0 >> 16));
          acc10 += b * bf2f((unsigned short)u1); acc11 += b * bf2f((unsigned short)(u1 >> 16));
          acc20 += b * bf2f((unsigned short)u2); acc21 += b * bf2f((unsigned short)(u2 >> 16));
        }
      }
    }
    for (int c = 4; c < nch; c++) {
      int idx = c * 8 + slot;
      float beta = 0.f; int sv = 0;
      if (idx < deg) {
        sv = srcs[ro + idx];
        float av[3], lv[3];
        edge_vals(P, Nsz, sv, h, qa, qw, av, lv);
        float align = -(fabsf(av[0]-av[1]) + fabsf(av[0]-av[2]) + fabsf(av[1]-av[2])) * (1.f/3.f);
        float t = (lv[0]*__expf(av[0])*rA0 + lv[1]*__expf(av[1])*rA1 + lv[2]*__expf(av[2])*rA2)
                  * (__expf(align) * rAl);
        beta = __expf(t) * rT;
      }
      int jmax = min(8, deg - c * 8);
      for (int jj = 0; jj < jmax; jj++) {
        float b = __shfl(beta, jj * 8 + hl, 64);
        int s = __shfl(sv, jj * 8, 64);
        size_t base9 = ((size_t)9 * Nsz + s) * 64 + lane;
        unsigned int u0 = Pu[base9];
        unsigned int u1 = Pu[base9 + Nsz * 64];
        unsigned int u2 = Pu[base9 + 2 * Nsz * 64];
        acc00 += b * bf2f((unsigned short)u0); acc01 += b * bf2f((unsigned short)(u0 >> 16));
        acc10 += b * bf2f((unsigned short)u1); acc11 += b * bf2f((unsigned short)(u1 >> 16));
        acc20 += b * bf2f((unsigned short)u2); acc21 += b * bf2f((unsigned short)(u2 >> 16));
      }
    }
  }
  unsigned int* ho = (unsigned int*)hagg;
  ho[((size_t)0 * N + n) * 64 + lane] = ((unsigned int)f2bf(acc01) << 16) | f2bf(acc00);
  ho[((size_t)1 * N + n) * 64 + lane] = ((unsigned int)f2bf(acc11) << 16) | f2bf(acc10);
  ho[((size_t)2 * N + n) * 64 + lane] = ((unsigned int)f2bf(acc21) << 16) | f2bf(acc20);
}

// one 64-row output tile for ONE 64-column half; Wa half pre-staged in Wt
__device__ __forceinline__ void out_tile_half(
    int t, int half, const unsigned short* __restrict__ Hagg,
    const float* __restrict__ ba,
    const float* __restrict__ x0, const float* __restrict__ x1,
    const float* __restrict__ x2, float alpha,
    float* __restrict__ out, int N, const unsigned short* Wt, int tid)
{
  int m = t % 3, rt = t / 3;
  const float* X = (m == 0) ? x0 : ((m == 1) ? x1 : x2);
  float oma = 1.f - alpha;
  int wave = tid >> 6, lane = tid & 63;
  int quad = lane >> 4, l16 = lane & 15;
  int row0 = rt * 64 + wave * 16;
  int arow = row0 + l16; if (arow >= N) arow = N - 1;
  const unsigned short* hp = Hagg + ((size_t)m * N + arow) * D;
  floatx4 acc[4];
#pragma unroll
  for (int ct = 0; ct < 4; ct++) acc[ct] = (floatx4)0.f;
#pragma unroll
  for (int kk = 0; kk < 128; kk += 32) {
    uint4 au = *(const uint4*)(hp + kk + quad * 8);
    bf16x8 af = __builtin_bit_cast(bf16x8, au);
#pragma unroll
    for (int ct = 0; ct < 4; ct++) {
      uint4 bu = *(const uint4*)(&Wt[(ct * 16 + l16) * 136 + kk + quad * 8]);
      bf16x8 bf = __builtin_bit_cast(bf16x8, bu);
      acc[ct] = __builtin_amdgcn_mfma_f32_16x16x32_bf16(af, bf, acc[ct], 0, 0, 0);
    }
  }
  float* om = out + (size_t)m * N * D;
#pragma unroll
  for (int ct = 0; ct < 4; ct++) {
    int col = half * 64 + ct * 16 + l16;
    float bias = ba[col];
#pragma unroll
    for (int i = 0; i < 4; i++) {
      int r = row0 + quad * 4 + i;
      if (r < N) {
        om[(size_t)r * D + col] =
            (acc[ct][i] + bias) * alpha + X[(size_t)r * D + col] * oma;
      }
    }
  }
}

// =============== multi-kernel path (primary) ================================
__global__ __launch_bounds__(256) void fb_misc(
    const float* Wk, const float* bk, const float* Wq, const float* bq,
    const float* Wv, const float* bv,
    const float* rel_att, const float* rel_msg, const float* rel_pri,
    const float* wm0, const float* wm1, const float* wm2,
    unsigned short* Wt_all, float* bias_all,
    const int* dst, int* counts, int E)
{
  int b = blockIdx.x;
  if (b < 384) {
    int g = b * 256 + threadIdx.x;
    if (g < 6 * 16384)
      fold_item(g, Wk, bk, Wq, bq, Wv, bv, rel_att, rel_msg, rel_pri,
                wm0, wm1, wm2, Wt_all, bias_all);
  } else {
    int e = (b - 384) * 256 + threadIdx.x;
    if (e < E) atomicAdd(&counts[dst[e]], 1);
  }
}

__global__ __launch_bounds__(256) void fb_projassign(
    const float* x0, const float* x1, const float* x2,
    const unsigned short* Wt_all, const float* bias_all,
    unsigned short* P, const int* counts, int* row_start, int* cursor,
    int* allocg, int N)
{
  __shared__ __attribute__((aligned(16))) unsigned short Wt[64 * 136];
  int ntiles = ((N + 63) / 64) * 3;
  int b = blockIdx.x;
  if (b < ntiles) {
    proj_tile(b, x0, x1, x2, Wt_all, bias_all, P, N, Wt, threadIdx.x);
  } else {
    int a = (b - ntiles) * 4 + (threadIdx.x >> 6);
    if (a < (N + 63) / 64)
      assign_chunk(a, counts, row_start, cursor, allocg, N, threadIdx.x & 63);
  }
}

__global__ void fb_scatter(const int* dst, const int* src, int* cursor,
                           int* src_sorted, int E) {
  int e = blockIdx.x * 256 + threadIdx.x;
  if (e < E) {
    int d = dst[e];
    int pos = atomicAdd(&cursor[d], 1);
    src_sorted[pos] = src[e];
  }
}

// fb_node: 512-thread blocks (8 waves = 2 waves/SIMD forced residency).
// r4: at 256-thr blocks HW kept only ~5.3 waves/CU (16.5%) despite headroom.
// r5: 1024-thr blocks forced a 128-reg cap and the allocator overshot to 64
//     VGPR -> catastrophic spill (WRITE 15->449MB). Lesson: node_one needs
//     cap >= 256. 512-thr blocks: launch_bounds(512) -> cap 512/2 = 256,
//     natural 112-VGPR codegen untouched, and >= 8 waves/CU structurally
//     (2 blocks/CU = 16 waves possible: 4 waves/SIMD x 112 = 448 <= 512).
__global__ __launch_bounds__(512) void fb_node(
    const unsigned short* P, const int* row_start, const int* counts,
    const int* srcs, unsigned short* hagg, int N)
{
  int n = blockIdx.x * 8 + (threadIdx.x >> 6);
  if (n < N) node_one(n, P, row_start, counts, srcs, hagg, N, threadIdx.x & 63);
}

__global__ __launch_bounds__(256) void fb_out(
    const unsigned short* Hagg, const float* Wa, const float* ba,
    const float* x0, const float* x1, const float* x2, const float* skip,
    float* out, int N)
{
  __shared__ __attribute__((aligned(16))) unsigned short Wt[64 * 136];
  int tid = threadIdx.x;
  float alpha = 1.f / (1.f + __expf(-skip[0]));
  for (int half = 0; half < 2; half++) {
    __syncthreads();
#pragma unroll
    for (int it = 0; it < 8; it++) {
      int idx = it * 256 + tid;
      int k = idx >> 4;
      int c4 = (idx & 15) << 2;
      float4 w = *(const float4*)(&Wa[k * 128 + half * 64 + c4]);
      Wt[(c4 + 0) * 136 + k] = f2bf(w.x);
      Wt[(c4 + 1) * 136 + k] = f2bf(w.y);
      Wt[(c4 + 2) * 136 + k] = f2bf(w.z);
      Wt[(c4 + 3) * 136 + k] = f2bf(w.w);
    }
    __syncthreads();
    out_tile_half(blockIdx.x, half, Hagg, ba, x0, x1, x2, alpha, out, N, Wt, tid);
  }
}

// ---------------------------------------------------------------- launch
extern "C" void kernel_launch(void* const* d_in, const int* in_sizes, int n_in,
                              void* d_out, int out_size, void* d_ws, size_t ws_size,
                              hipStream_t stream) {
  const float* x0 = (const float*)d_in[0];
  const float* x1 = (const float*)d_in[1];
  const float* x2 = (const float*)d_in[2];
  const float* Wk = (const float*)d_in[3];
  const float* bk = (const float*)d_in[4];
  const float* Wq = (const float*)d_in[5];
  const float* bq = (const float*)d_in[6];
  const float* Wv = (const float*)d_in[7];
  const float* bv = (const float*)d_in[8];
  const float* Wa = (const float*)d_in[9];
  const float* ba = (const float*)d_in[10];
  const float* rel_att = (const float*)d_in[11];
  const float* rel_msg = (const float*)d_in[12];
  const float* rel_pri = (const float*)d_in[13];
  const float* wm0 = (const float*)d_in[14];
  const float* wm1 = (const float*)d_in[15];
  const float* wm2 = (const float*)d_in[16];
  const float* skip = (const float*)d_in[17];
  const int* src = (const int*)d_in[18];
  const int* dstv = (const int*)d_in[19];
  int N = in_sizes[0] / D;      // 20000
  int E = in_sizes[18];         // 160000

  char* wsb = (char*)d_ws;
  size_t off = 0;
  auto alloc_b = [&](size_t bytes) { size_t o = off; off += (bytes + 63) & ~(size_t)63; return o; };
  unsigned short* P         = (unsigned short*)(wsb + alloc_b((size_t)12 * N * D * 2));
  unsigned short* Wt_all    = (unsigned short*)(wsb + alloc_b((size_t)6 * 16384 * 2));
  float*          bias_all  = (float*)(wsb + alloc_b((size_t)6 * 128 * 4));
  // ctrl: bar[8*16] | alloc[16] | counts[N] | cursor[N]
  int*            ctrl      = (int*)(wsb + alloc_b(((size_t)144 + 2 * N) * 4));
  int*            row_start = (int*)(wsb + alloc_b((size_t)(N + 1) * 4));
  int*            src_sorted= (int*)(wsb + alloc_b((size_t)E * 4));
  unsigned short* hagg      = (unsigned short*)(wsb + alloc_b((size_t)3 * N * D * 2));
  int* allocg = ctrl + 128;
  int* counts = ctrl + 144;
  int* cursor = ctrl + 144 + N;

  // zero alloc + counts (cursor written by assign phase)
  hipMemsetAsync(ctrl, 0, ((size_t)144 + N) * sizeof(int), stream);

  int ntiles = ((N + 63) / 64) * 3;
  int nchunks = (N + 63) / 64;
  fb_misc<<<dim3(384 + (E + 255) / 256), 256, 0, stream>>>(
      Wk, bk, Wq, bq, Wv, bv, rel_att, rel_msg, rel_pri, wm0, wm1, wm2,
      Wt_all, bias_all, dstv, counts, E);
  fb_projassign<<<dim3(ntiles + (nchunks + 3) / 4), 256, 0, stream>>>(
      x0, x1, x2, Wt_all, bias_all, P, counts, row_start, cursor, allocg, N);
  fb_scatter<<<dim3((E + 255) / 256), 256, 0, stream>>>(
      dstv, src, cursor, src_sorted, E);
  fb_node<<<dim3((N + 7) / 8), 512, 0, stream>>>(
      P, row_start, counts, src_sorted, hagg, N);
  fb_out<<<dim3(ntiles), 256, 0, stream>>>(
      hagg, Wa, ba, x0, x1, x2, skip, (float*)d_out, N);
}

// Round 7
// 253.246 us; speedup vs baseline: 1.5783x; 1.0071x over previous
//
#include <hip/hip_runtime.h>

#define D 128
#define NH 8

typedef __bf16 bf16x8 __attribute__((ext_vector_type(8)));
typedef unsigned short ushortx8 __attribute__((ext_vector_type(8)));
typedef float floatx4 __attribute__((ext_vector_type(4)));

__device__ __forceinline__ float bf2f(unsigned short u) {
  union { unsigned int i; float f; } x; x.i = ((unsigned int)u) << 16; return x.f;
}
__device__ __forceinline__ unsigned short f2bf(float f) {
  union { float f; unsigned int i; } x; x.f = f;
  unsigned int i = x.i;
  return (unsigned short)((i + 0x7FFFu + ((i >> 16) & 1u)) >> 16);
}
__device__ __forceinline__ void acc2(unsigned int ku, unsigned int qu, float& s) {
  union { unsigned int i; float f; } a, b;
  a.i = ku << 16;          b.i = qu << 16;          s += a.f * b.f;
  a.i = ku & 0xffff0000u;  b.i = qu & 0xffff0000u;  s += a.f * b.f;
}

// =============== phase helpers (proven bodies) ==============================
// weight fold: p0 Wk ; p1 Wq.rel_attT * pri*2.5 ; p2..4 Wq.wm_mT ; p5 Wv.rel_msg
__device__ __forceinline__ void fold_item(
    int gid,
    const float* __restrict__ Wk, const float* __restrict__ bk,
    const float* __restrict__ Wq, const float* __restrict__ bq,
    const float* __restrict__ Wv, const float* __restrict__ bv,
    const float* __restrict__ rel_att, const float* __restrict__ rel_msg,
    const float* __restrict__ rel_pri,
    const float* __restrict__ wm0, const float* __restrict__ wm1,
    const float* __restrict__ wm2,
    unsigned short* __restrict__ Wt_all, float* __restrict__ bias_all)
{
  int p = gid >> 14;
  int idx = gid & 16383;
  int c = idx >> 7, k = idx & 127;
  int h = c >> 4, r = c & 15;
  float wsum = 0.f, bsum = 0.f;
  if (p == 0) {
    wsum = Wk[k * 128 + c];
    bsum = bk[c];
  } else if (p <= 4) {
    const float* M = (p == 1) ? rel_att : ((p == 2) ? wm0 : ((p == 3) ? wm1 : wm2));
#pragma unroll
    for (int f = 0; f < 16; f++) {
      float mv = M[h * 256 + r * 16 + f];
      wsum += Wq[k * 128 + h * 16 + f] * mv;
      bsum += bq[h * 16 + f] * mv;
    }
    if (p == 1) { float sc = rel_pri[h] * 2.5f; wsum *= sc; bsum *= sc; }
  } else {
#pragma unroll
    for (int d = 0; d < 16; d++) {
      float mv = rel_msg[h * 256 + d * 16 + r];
      wsum += Wv[k * 128 + h * 16 + d] * mv;
      bsum += bv[h * 16 + d] * mv;
    }
  }
  Wt_all[(size_t)p * 16384 + c * 128 + k] = f2bf(wsum);
  if (k == 0) bias_all[p * 128 + c] = bsum;
}

// one 64-row x 4-plane projection tile, 256 threads.
// Output layouts (r6 change, for fb_node's TA-throughput):
//   pt=0 (K):  Pk[node][m][128]          — per-node 768B row (gather locality)
//   pt=1,2(q): Pq[(qplane)][N][128]      — unchanged (qplane = (pt-1)*3+m)
//   pt=3 (V):  Pv[node][64][4] uints     — uint j=(col>>1) pair, slot m, pad w
__device__ __forceinline__ void proj_tile(
    int t, const float* __restrict__ x0, const float* __restrict__ x1,
    const float* __restrict__ x2,
    const unsigned short* __restrict__ Wt_all, const float* __restrict__ bias_all,
    unsigned short* __restrict__ Pk, unsigned short* __restrict__ Pq,
    unsigned short* __restrict__ Pv,
    int N, unsigned short* Wt, int tid)
{
  int m = t % 3, rt = t / 3;
  const float* X = (m == 0) ? x0 : ((m == 1) ? x1 : x2);
  int wave = tid >> 6, lane = tid & 63;
  int quad = lane >> 4, l16 = lane & 15;
  int row0 = rt * 64 + wave * 16;
  int arow = row0 + l16; if (arow >= N) arow = N - 1;
  const float* ap = X + (size_t)arow * D;
  bf16x8 afr[4];
#pragma unroll
  for (int kk4 = 0; kk4 < 4; kk4++) {
    float4 f0 = *(const float4*)(ap + kk4 * 32 + quad * 8);
    float4 f1 = *(const float4*)(ap + kk4 * 32 + quad * 8 + 4);
    ushortx8 uu;
    uu[0]=f2bf(f0.x); uu[1]=f2bf(f0.y); uu[2]=f2bf(f0.z); uu[3]=f2bf(f0.w);
    uu[4]=f2bf(f1.x); uu[5]=f2bf(f1.y); uu[6]=f2bf(f1.z); uu[7]=f2bf(f1.w);
    afr[kk4] = __builtin_bit_cast(bf16x8, uu);
  }
  for (int pt = 0; pt < 4; pt++) {
    int wp = (pt == 0) ? 0 : ((pt == 1) ? 1 : ((pt == 2) ? (2 + m) : 5));
    const unsigned short* Wsrc = Wt_all + (size_t)wp * 16384;
    const float* B = bias_all + wp * 128;
    for (int half = 0; half < 2; half++) {
      __syncthreads();
#pragma unroll
      for (int it = 0; it < 4; it++) {
        int idx = it * 256 + tid;            // 0..1023
        int c = idx >> 4, kc = (idx & 15) << 3;
        *(uint4*)(&Wt[c * 136 + kc]) =
            *(const uint4*)(&Wsrc[(half * 64 + c) * 128 + kc]);
      }
      __syncthreads();
      floatx4 acc[4];
#pragma unroll
      for (int ct = 0; ct < 4; ct++) acc[ct] = (floatx4)0.f;
#pragma unroll
      for (int kk4 = 0; kk4 < 4; kk4++) {
#pragma unroll
        for (int ct2 = 0; ct2 < 4; ct2++) {
          uint4 bu = *(const uint4*)(&Wt[(ct2 * 16 + l16) * 136 + kk4 * 32 + quad * 8]);
          bf16x8 bf = __builtin_bit_cast(bf16x8, bu);
          acc[ct2] =
              __builtin_amdgcn_mfma_f32_16x16x32_bf16(afr[kk4], bf, acc[ct2], 0, 0, 0);
        }
      }
#pragma unroll
      for (int ct2 = 0; ct2 < 4; ct2++) {
        int col = half * 64 + ct2 * 16 + l16;
        float bias = B[col];
#pragma unroll
        for (int i = 0; i < 4; i++) {
          int r = row0 + quad * 4 + i;
          if (r < N) {
            unsigned short v = f2bf(acc[ct2][i] + bias);
            if (pt == 0) {
              Pk[((size_t)r * 3 + m) * 128 + col] = v;
            } else if (pt == 3) {
              Pv[(((size_t)r * 64 + (col >> 1)) * 4 + m) * 2 + (col & 1)] = v;
            } else {
              Pq[(size_t)((pt - 1) * 3 + m) * N * 128 + (size_t)r * 128 + col] = v;
            }
          }
        }
      }
    }
  }
}

// unordered CSR segment assignment: one wave handles 64 nodes, one atomicAdd
__device__ __forceinline__ void assign_chunk(
    int a, const int* __restrict__ counts, int* __restrict__ row_start,
    int* __restrict__ cursor, int* __restrict__ allocg, int N, int lane)
{
  int n = a * 64 + lane;
  int cnt = (n < N) ? counts[n] : 0;
  int x = cnt;
#pragma unroll
  for (int off = 1; off < 64; off <<= 1) {
    int y = __shfl_up(x, off, 64);
    if (lane >= off) x += y;
  }
  int wtot = __shfl(x, 63, 64);
  int wbase = 0;
  if (lane == 63) wbase = atomicAdd(allocg, wtot);
  wbase = __shfl(wbase, 63, 64);
  if (n < N) { int v = wbase + x - cnt; row_start[n] = v; cursor[n] = v; }
}

// one dst node per wave — round-8 body; K reads from per-node Pk rows.
__device__ __forceinline__ void edge_vals(
    const unsigned short* __restrict__ Pk, int s, int h,
    const uint4 (&qa)[3][2], const uint4 (&qw)[3][2],
    float (&av)[3], float (&lv)[3])
{
  const unsigned short* krow = Pk + (size_t)s * 384;   // [3][128] bf16
#pragma unroll
  for (int m = 0; m < 3; m++) {
    const unsigned short* kp = krow + m * 128 + h * 16;
    uint4 k0 = *(const uint4*)kp, k1 = *(const uint4*)(kp + 8);
    const unsigned int* ka = (const unsigned int*)&k0;
    const unsigned int* kb = (const unsigned int*)&k1;
    const unsigned int* a0 = (const unsigned int*)&qa[m][0];
    const unsigned int* a1 = (const unsigned int*)&qa[m][1];
    const unsigned int* w0 = (const unsigned int*)&qw[m][0];
    const unsigned int* w1 = (const unsigned int*)&qw[m][1];
    float da = 0.f, dw = 0.f;
#pragma unroll
    for (int j = 0; j < 4; j++) {
      acc2(ka[j], a0[j], da); acc2(kb[j], a1[j], da);
      acc2(ka[j], w0[j], dw); acc2(kb[j], w1[j], dw);
    }
    av[m] = da;
    lv[m] = dw;
  }
  float mx = fmaxf(lv[0], fmaxf(lv[1], lv[2]));
  float e0 = __expf(lv[0] - mx), e1 = __expf(lv[1] - mx), e2 = __expf(lv[2] - mx);
  float inv = 1.f / (e0 + e1 + e2);
  lv[0] = e0 * inv; lv[1] = e1 * inv; lv[2] = e2 * inv;
}

__device__ __forceinline__ void node_one(
    int n, const unsigned short* __restrict__ Pk,
    const unsigned short* __restrict__ Pq, const unsigned short* __restrict__ Pv,
    const int* __restrict__ row_start, const int* __restrict__ counts,
    const int* __restrict__ srcs, unsigned short* __restrict__ hagg,
    int N, int lane)
{
  int ro = row_start[n];
  int deg = counts[n];
  float acc00 = 0, acc01 = 0, acc10 = 0, acc11 = 0, acc20 = 0, acc21 = 0;
  if (deg > 0) {
    int h = lane & 7, slot = lane >> 3;
    size_t Nsz = (size_t)N;
    uint4 qa[3][2], qw[3][2];
#pragma unroll
    for (int m = 0; m < 3; m++) {
      const unsigned short* qap = Pq + ((size_t)m * Nsz + n) * 128 + h * 16;
      const unsigned short* qwp = Pq + ((size_t)(3 + m) * Nsz + n) * 128 + h * 16;
      qa[m][0] = *(const uint4*)qap; qa[m][1] = *(const uint4*)(qap + 8);
      qw[m][0] = *(const uint4*)qwp; qw[m][1] = *(const uint4*)(qwp + 8);
    }
    int nch = (deg + 7) >> 3;
    float cX0[4] = {}, cX1[4] = {}, cX2[4] = {}, cEa[4] = {}, cT[4] = {};
    int cS[4] = {};
    float sA0 = 0, sA1 = 0, sA2 = 0, sAl = 0;
#pragma unroll
    for (int c = 0; c < 4; c++) {
      int idx = c * 8 + slot;
      if (c < nch && idx < deg) {
        int s = srcs[ro + idx]; cS[c] = s;
        float av[3], lv[3];
        edge_vals(Pk, s, h, qa, qw, av, lv);
        float e0 = __expf(av[0]), e1 = __expf(av[1]), e2 = __expf(av[2]);
        float align = -(fabsf(av[0]-av[1]) + fabsf(av[0]-av[2]) + fabsf(av[1]-av[2])) * (1.f/3.f);
        float ea = __expf(align);
        cX0[c] = lv[0] * e0; cX1[c] = lv[1] * e1; cX2[c] = lv[2] * e2; cEa[c] = ea;
        sA0 += e0; sA1 += e1; sA2 += e2; sAl += ea;
      }
    }
    for (int c = 4; c < nch; c++) {
      int idx = c * 8 + slot;
      if (idx < deg) {
        int s = srcs[ro + idx];
        float av[3], lv[3];
        edge_vals(Pk, s, h, qa, qw, av, lv);
        float align = -(fabsf(av[0]-av[1]) + fabsf(av[0]-av[2]) + fabsf(av[1]-av[2])) * (1.f/3.f);
        sA0 += __expf(av[0]); sA1 += __expf(av[1]); sA2 += __expf(av[2]);
        sAl += __expf(align);
      }
    }
#pragma unroll
    for (int off = 8; off < 64; off <<= 1) {
      sA0 += __shfl_xor(sA0, off, 64);
      sA1 += __shfl_xor(sA1, off, 64);
      sA2 += __shfl_xor(sA2, off, 64);
      sAl += __shfl_xor(sAl, off, 64);
    }
    float rA0 = 1.f / fmaxf(sA0, 1e-30f), rA1 = 1.f / fmaxf(sA1, 1e-30f);
    float rA2 = 1.f / fmaxf(sA2, 1e-30f), rAl = 1.f / fmaxf(sAl, 1e-30f);
    float sT = 0;
#pragma unroll
    for (int c = 0; c < 4; c++) {
      int idx = c * 8 + slot;
      if (c < nch && idx < deg) {
        float t = (cX0[c] * rA0 + cX1[c] * rA1 + cX2[c] * rA2) * (cEa[c] * rAl);
        cT[c] = t;
        sT += __expf(t);
      }
    }
    for (int c = 4; c < nch; c++) {
      int idx = c * 8 + slot;
      if (idx < deg) {
        int s = srcs[ro + idx];
        float av[3], lv[3];
        edge_vals(Pk, s, h, qa, qw, av, lv);
        float align = -(fabsf(av[0]-av[1]) + fabsf(av[0]-av[2]) + fabsf(av[1]-av[2])) * (1.f/3.f);
        float t = (lv[0]*__expf(av[0])*rA0 + lv[1]*__expf(av[1])*rA1 + lv[2]*__expf(av[2])*rA2)
                  * (__expf(align) * rAl);
        sT += __expf(t);
      }
    }
#pragma unroll
    for (int off = 8; off < 64; off <<= 1) sT += __shfl_xor(sT, off, 64);
    float rT = 1.f / fmaxf(sT, 1e-30f);
    const uint4* Pv4 = (const uint4*)Pv;
    int hl = lane >> 3;
#pragma unroll
    for (int c = 0; c < 4; c++) {
      if (c < nch) {
        int idx = c * 8 + slot;
        float beta = (idx < deg) ? __expf(cT[c]) * rT : 0.f;
        int sv = cS[c];
        float bj[8]; int sj[8];
#pragma unroll
        for (int jj = 0; jj < 8; jj++) {
          bj[jj] = __shfl(beta, jj * 8 + hl, 64);
          sj[jj] = __shfl(sv, jj * 8, 64);
        }
#pragma unroll
        for (int jj = 0; jj < 8; jj++) {
          // one dwordx4: V pair (2*lane, 2*lane+1) for all 3 modalities (+pad)
          uint4 v4 = Pv4[(size_t)sj[jj] * 64 + lane];
          float b = bj[jj];
          acc00 += b * bf2f((unsigned short)v4.x); acc01 += b * bf2f((unsigned short)(v4.x >> 16));
          acc10 += b * bf2f((unsigned short)v4.y); acc11 += b * bf2f((unsigned short)(v4.y >> 16));
          acc20 += b * bf2f((unsigned short)v4.z); acc21 += b * bf2f((unsigned short)(v4.z >> 16));
        }
      }
    }
    for (int c = 4; c < nch; c++) {
      int idx = c * 8 + slot;
      float beta = 0.f; int sv = 0;
      if (idx < deg) {
        sv = srcs[ro + idx];
        float av[3], lv[3];
        edge_vals(Pk, sv, h, qa, qw, av, lv);
        float align = -(fabsf(av[0]-av[1]) + fabsf(av[0]-av[2]) + fabsf(av[1]-av[2])) * (1.f/3.f);
        float t = (lv[0]*__expf(av[0])*rA0 + lv[1]*__expf(av[1])*rA1 + lv[2]*__expf(av[2])*rA2)
                  * (__expf(align) * rAl);
        beta = __expf(t) * rT;
      }
      int jmax = min(8, deg - c * 8);
      for (int jj = 0; jj < jmax; jj++) {
        float b = __shfl(beta, jj * 8 + hl, 64);
        int s = __shfl(sv, jj * 8, 64);
        uint4 v4 = Pv4[(size_t)s * 64 + lane];
        acc00 += b * bf2f((unsigned short)v4.x); acc01 += b * bf2f((unsigned short)(v4.x >> 16));
        acc10 += b * bf2f((unsigned short)v4.y); acc11 += b * bf2f((unsigned short)(v4.y >> 16));
        acc20 += b * bf2f((unsigned short)v4.z); acc21 += b * bf2f((unsigned short)(v4.z >> 16));
      }
    }
  }
  unsigned int* ho = (unsigned int*)hagg;
  ho[((size_t)0 * N + n) * 64 + lane] = ((unsigned int)f2bf(acc01) << 16) | f2bf(acc00);
  ho[((size_t)1 * N + n) * 64 + lane] = ((unsigned int)f2bf(acc11) << 16) | f2bf(acc10);
  ho[((size_t)2 * N + n) * 64 + lane] = ((unsigned int)f2bf(acc21) << 16) | f2bf(acc20);
}

// one 64-row output tile for ONE 64-column half; Wa half pre-staged in Wt
__device__ __forceinline__ void out_tile_half(
    int t, int half, const unsigned short* __restrict__ Hagg,
    const float* __restrict__ ba,
    const float* __restrict__ x0, const float* __restrict__ x1,
    const float* __restrict__ x2, float alpha,
    float* __restrict__ out, int N, const unsigned short* Wt, int tid)
{
  int m = t % 3, rt = t / 3;
  const float* X = (m == 0) ? x0 : ((m == 1) ? x1 : x2);
  float oma = 1.f - alpha;
  int wave = tid >> 6, lane = tid & 63;
  int quad = lane >> 4, l16 = lane & 15;
  int row0 = rt * 64 + wave * 16;
  int arow = row0 + l16; if (arow >= N) arow = N - 1;
  const unsigned short* hp = Hagg + ((size_t)m * N + arow) * D;
  floatx4 acc[4];
#pragma unroll
  for (int ct = 0; ct < 4; ct++) acc[ct] = (floatx4)0.f;
#pragma unroll
  for (int kk = 0; kk < 128; kk += 32) {
    uint4 au = *(const uint4*)(hp + kk + quad * 8);
    bf16x8 af = __builtin_bit_cast(bf16x8, au);
#pragma unroll
    for (int ct = 0; ct < 4; ct++) {
      uint4 bu = *(const uint4*)(&Wt[(ct * 16 + l16) * 136 + kk + quad * 8]);
      bf16x8 bf = __builtin_bit_cast(bf16x8, bu);
      acc[ct] = __builtin_amdgcn_mfma_f32_16x16x32_bf16(af, bf, acc[ct], 0, 0, 0);
    }
  }
  float* om = out + (size_t)m * N * D;
#pragma unroll
  for (int ct = 0; ct < 4; ct++) {
    int col = half * 64 + ct * 16 + l16;
    float bias = ba[col];
#pragma unroll
    for (int i = 0; i < 4; i++) {
      int r = row0 + quad * 4 + i;
      if (r < N) {
        om[(size_t)r * D + col] =
            (acc[ct][i] + bias) * alpha + X[(size_t)r * D + col] * oma;
      }
    }
  }
}

// =============== multi-kernel path (primary) ================================
__global__ __launch_bounds__(256) void fb_misc(
    const float* Wk, const float* bk, const float* Wq, const float* bq,
    const float* Wv, const float* bv,
    const float* rel_att, const float* rel_msg, const float* rel_pri,
    const float* wm0, const float* wm1, const float* wm2,
    unsigned short* Wt_all, float* bias_all,
    const int* dst, int* counts, int E)
{
  int b = blockIdx.x;
  if (b < 384) {
    int g = b * 256 + threadIdx.x;
    if (g < 6 * 16384)
      fold_item(g, Wk, bk, Wq, bq, Wv, bv, rel_att, rel_msg, rel_pri,
                wm0, wm1, wm2, Wt_all, bias_all);
  } else {
    int e = (b - 384) * 256 + threadIdx.x;
    if (e < E) atomicAdd(&counts[dst[e]], 1);
  }
}

__global__ __launch_bounds__(256) void fb_projassign(
    const float* x0, const float* x1, const float* x2,
    const unsigned short* Wt_all, const float* bias_all,
    unsigned short* Pk, unsigned short* Pq, unsigned short* Pv,
    const int* counts, int* row_start, int* cursor,
    int* allocg, int N)
{
  __shared__ __attribute__((aligned(16))) unsigned short Wt[64 * 136];
  int ntiles = ((N + 63) / 64) * 3;
  int b = blockIdx.x;
  if (b < ntiles) {
    proj_tile(b, x0, x1, x2, Wt_all, bias_all, Pk, Pq, Pv, N, Wt, threadIdx.x);
  } else {
    int a = (b - ntiles) * 4 + (threadIdx.x >> 6);
    if (a < (N + 63) / 64)
      assign_chunk(a, counts, row_start, cursor, allocg, N, threadIdx.x & 63);
  }
}

__global__ void fb_scatter(const int* dst, const int* src, int* cursor,
                           int* src_sorted, int E) {
  int e = blockIdx.x * 256 + threadIdx.x;
  if (e < E) {
    int d = dst[e];
    int pos = atomicAdd(&cursor[d], 1);
    src_sorted[pos] = src[e];
  }
}

// fb_node: 256-thr blocks (r4 best). r6 showed more waves/CU doesn't help ->
// TA/VMEM-throughput-bound; this round cuts VMEM instr ~46->30 per node via
// the Pk/Pv layouts (see proj_tile header comment).
__global__ __launch_bounds__(256) void fb_node(
    const unsigned short* Pk, const unsigned short* Pq, const unsigned short* Pv,
    const int* row_start, const int* counts,
    const int* srcs, unsigned short* hagg, int N)
{
  int n = blockIdx.x * 4 + (threadIdx.x >> 6);
  if (n < N) node_one(n, Pk, Pq, Pv, row_start, counts, srcs, hagg, N, threadIdx.x & 63);
}

__global__ __launch_bounds__(256) void fb_out(
    const unsigned short* Hagg, const float* Wa, const float* ba,
    const float* x0, const float* x1, const float* x2, const float* skip,
    float* out, int N)
{
  __shared__ __attribute__((aligned(16))) unsigned short Wt[64 * 136];
  int tid = threadIdx.x;
  float alpha = 1.f / (1.f + __expf(-skip[0]));
  for (int half = 0; half < 2; half++) {
    __syncthreads();
#pragma unroll
    for (int it = 0; it < 8; it++) {
      int idx = it * 256 + tid;
      int k = idx >> 4;
      int c4 = (idx & 15) << 2;
      float4 w = *(const float4*)(&Wa[k * 128 + half * 64 + c4]);
      Wt[(c4 + 0) * 136 + k] = f2bf(w.x);
      Wt[(c4 + 1) * 136 + k] = f2bf(w.y);
      Wt[(c4 + 2) * 136 + k] = f2bf(w.z);
      Wt[(c4 + 3) * 136 + k] = f2bf(w.w);
    }
    __syncthreads();
    out_tile_half(blockIdx.x, half, Hagg, ba, x0, x1, x2, alpha, out, N, Wt, tid);
  }
}

// ---------------------------------------------------------------- launch
extern "C" void kernel_launch(void* const* d_in, const int* in_sizes, int n_in,
                              void* d_out, int out_size, void* d_ws, size_t ws_size,
                              hipStream_t stream) {
  const float* x0 = (const float*)d_in[0];
  const float* x1 = (const float*)d_in[1];
  const float* x2 = (const float*)d_in[2];
  const float* Wk = (const float*)d_in[3];
  const float* bk = (const float*)d_in[4];
  const float* Wq = (const float*)d_in[5];
  const float* bq = (const float*)d_in[6];
  const float* Wv = (const float*)d_in[7];
  const float* bv = (const float*)d_in[8];
  const float* Wa = (const float*)d_in[9];
  const float* ba = (const float*)d_in[10];
  const float* rel_att = (const float*)d_in[11];
  const float* rel_msg = (const float*)d_in[12];
  const float* rel_pri = (const float*)d_in[13];
  const float* wm0 = (const float*)d_in[14];
  const float* wm1 = (const float*)d_in[15];
  const float* wm2 = (const float*)d_in[16];
  const float* skip = (const float*)d_in[17];
  const int* src = (const int*)d_in[18];
  const int* dstv = (const int*)d_in[19];
  int N = in_sizes[0] / D;      // 20000
  int E = in_sizes[18];         // 160000

  char* wsb = (char*)d_ws;
  size_t off = 0;
  auto alloc_b = [&](size_t bytes) { size_t o = off; off += (bytes + 63) & ~(size_t)63; return o; };
  unsigned short* Pk        = (unsigned short*)(wsb + alloc_b((size_t)3 * N * D * 2));       // [N][3][128]
  unsigned short* Pq        = (unsigned short*)(wsb + alloc_b((size_t)6 * N * D * 2));       // [6][N][128]
  unsigned short* Pv        = (unsigned short*)(wsb + alloc_b((size_t)N * 64 * 4 * 4));      // [N][64][4] uints
  unsigned short* Wt_all    = (unsigned short*)(wsb + alloc_b((size_t)6 * 16384 * 2));
  float*          bias_all  = (float*)(wsb + alloc_b((size_t)6 * 128 * 4));
  // ctrl: bar[8*16] | alloc[16] | counts[N] | cursor[N]
  int*            ctrl      = (int*)(wsb + alloc_b(((size_t)144 + 2 * N) * 4));
  int*            row_start = (int*)(wsb + alloc_b((size_t)(N + 1) * 4));
  int*            src_sorted= (int*)(wsb + alloc_b((size_t)E * 4));
  unsigned short* hagg      = (unsigned short*)(wsb + alloc_b((size_t)3 * N * D * 2));
  int* allocg = ctrl + 128;
  int* counts = ctrl + 144;
  int* cursor = ctrl + 144 + N;

  // zero alloc + counts (cursor written by assign phase)
  hipMemsetAsync(ctrl, 0, ((size_t)144 + N) * sizeof(int), stream);

  int ntiles = ((N + 63) / 64) * 3;
  int nchunks = (N + 63) / 64;
  fb_misc<<<dim3(384 + (E + 255) / 256), 256, 0, stream>>>(
      Wk, bk, Wq, bq, Wv, bv, rel_att, rel_msg, rel_pri, wm0, wm1, wm2,
      Wt_all, bias_all, dstv, counts, E);
  fb_projassign<<<dim3(ntiles + (nchunks + 3) / 4), 256, 0, stream>>>(
      x0, x1, x2, Wt_all, bias_all, Pk, Pq, Pv, counts, row_start, cursor, allocg, N);
  fb_scatter<<<dim3((E + 255) / 256), 256, 0, stream>>>(
      dstv, src, cursor, src_sorted, E);
  fb_node<<<dim3((N + 3) / 4), 256, 0, stream>>>(
      Pk, Pq, Pv, row_start, counts, src_sorted, hagg, N);
  fb_out<<<dim3(ntiles), 256, 0, stream>>>(
      hagg, Wa, ba, x0, x1, x2, skip, (float*)d_out, N);
}

// Round 8
// 242.909 us; speedup vs baseline: 1.6455x; 1.0426x over previous
//
#include <hip/hip_runtime.h>

#define D 128
#define NH 8

typedef __bf16 bf16x8 __attribute__((ext_vector_type(8)));
typedef unsigned short ushortx8 __attribute__((ext_vector_type(8)));
typedef float floatx4 __attribute__((ext_vector_type(4)));

__device__ __forceinline__ float bf2f(unsigned short u) {
  union { unsigned int i; float f; } x; x.i = ((unsigned int)u) << 16; return x.f;
}
__device__ __forceinline__ unsigned short f2bf(float f) {
  union { float f; unsigned int i; } x; x.f = f;
  unsigned int i = x.i;
  return (unsigned short)((i + 0x7FFFu + ((i >> 16) & 1u)) >> 16);
}
__device__ __forceinline__ void acc2(unsigned int ku, unsigned int qu, float& s) {
  union { unsigned int i; float f; } a, b;
  a.i = ku << 16;          b.i = qu << 16;          s += a.f * b.f;
  a.i = ku & 0xffff0000u;  b.i = qu & 0xffff0000u;  s += a.f * b.f;
}

// =============== phase helpers (proven bodies) ==============================
// weight fold: p0 Wk ; p1 Wq.rel_attT * pri*2.5 ; p2..4 Wq.wm_mT ; p5 Wv.rel_msg
__device__ __forceinline__ void fold_item(
    int gid,
    const float* __restrict__ Wk, const float* __restrict__ bk,
    const float* __restrict__ Wq, const float* __restrict__ bq,
    const float* __restrict__ Wv, const float* __restrict__ bv,
    const float* __restrict__ rel_att, const float* __restrict__ rel_msg,
    const float* __restrict__ rel_pri,
    const float* __restrict__ wm0, const float* __restrict__ wm1,
    const float* __restrict__ wm2,
    unsigned short* __restrict__ Wt_all, float* __restrict__ bias_all)
{
  int p = gid >> 14;
  int idx = gid & 16383;
  int c = idx >> 7, k = idx & 127;
  int h = c >> 4, r = c & 15;
  float wsum = 0.f, bsum = 0.f;
  if (p == 0) {
    wsum = Wk[k * 128 + c];
    bsum = bk[c];
  } else if (p <= 4) {
    const float* M = (p == 1) ? rel_att : ((p == 2) ? wm0 : ((p == 3) ? wm1 : wm2));
#pragma unroll
    for (int f = 0; f < 16; f++) {
      float mv = M[h * 256 + r * 16 + f];
      wsum += Wq[k * 128 + h * 16 + f] * mv;
      bsum += bq[h * 16 + f] * mv;
    }
    if (p == 1) { float sc = rel_pri[h] * 2.5f; wsum *= sc; bsum *= sc; }
  } else {
#pragma unroll
    for (int d = 0; d < 16; d++) {
      float mv = rel_msg[h * 256 + d * 16 + r];
      wsum += Wv[k * 128 + h * 16 + d] * mv;
      bsum += bv[h * 16 + d] * mv;
    }
  }
  Wt_all[(size_t)p * 16384 + c * 128 + k] = f2bf(wsum);
  if (k == 0) bias_all[p * 128 + c] = bsum;
}

// one 64-row x 4-plane projection tile, 256 threads.
// r8 change: SWAPPED MFMA operands — mfma(bf, afr) computes D^T so each lane
// holds P[row = row0+l16][cols ct2*16+quad*4 .. +3] (4 consecutive bf16 = 8B)
// -> one dwordx2 store per ct2 instead of 16 scalar 2B stores per half.
// (A/B fragment layouts are symmetric on gfx950; swap is a pure relabel.)
__device__ __forceinline__ void proj_tile(
    int t, const float* __restrict__ x0, const float* __restrict__ x1,
    const float* __restrict__ x2,
    const unsigned short* __restrict__ Wt_all, const float* __restrict__ bias_all,
    unsigned short* __restrict__ P, int N, unsigned short* Wt, int tid)
{
  int m = t % 3, rt = t / 3;
  const float* X = (m == 0) ? x0 : ((m == 1) ? x1 : x2);
  int wave = tid >> 6, lane = tid & 63;
  int quad = lane >> 4, l16 = lane & 15;
  int row0 = rt * 64 + wave * 16;
  int arow = row0 + l16; if (arow >= N) arow = N - 1;
  const float* ap = X + (size_t)arow * D;
  bf16x8 afr[4];
#pragma unroll
  for (int kk4 = 0; kk4 < 4; kk4++) {
    float4 f0 = *(const float4*)(ap + kk4 * 32 + quad * 8);
    float4 f1 = *(const float4*)(ap + kk4 * 32 + quad * 8 + 4);
    ushortx8 uu;
    uu[0]=f2bf(f0.x); uu[1]=f2bf(f0.y); uu[2]=f2bf(f0.z); uu[3]=f2bf(f0.w);
    uu[4]=f2bf(f1.x); uu[5]=f2bf(f1.y); uu[6]=f2bf(f1.z); uu[7]=f2bf(f1.w);
    afr[kk4] = __builtin_bit_cast(bf16x8, uu);
  }
  int r = row0 + l16;                       // this lane's output row (swapped)
  for (int pt = 0; pt < 4; pt++) {
    int wp = (pt == 0) ? 0 : ((pt == 1) ? 1 : ((pt == 2) ? (2 + m) : 5));
    const unsigned short* Wsrc = Wt_all + (size_t)wp * 16384;
    const float* B = bias_all + wp * 128;
    unsigned short* Pout = P + (size_t)(pt * 3 + m) * N * D;
    for (int half = 0; half < 2; half++) {
      __syncthreads();
#pragma unroll
      for (int it = 0; it < 4; it++) {
        int idx = it * 256 + tid;            // 0..1023
        int c = idx >> 4, kc = (idx & 15) << 3;
        *(uint4*)(&Wt[c * 136 + kc]) =
            *(const uint4*)(&Wsrc[(half * 64 + c) * 128 + kc]);
      }
      __syncthreads();
      floatx4 acc[4];
#pragma unroll
      for (int ct = 0; ct < 4; ct++) acc[ct] = (floatx4)0.f;
#pragma unroll
      for (int kk4 = 0; kk4 < 4; kk4++) {
#pragma unroll
        for (int ct2 = 0; ct2 < 4; ct2++) {
          uint4 bu = *(const uint4*)(&Wt[(ct2 * 16 + l16) * 136 + kk4 * 32 + quad * 8]);
          bf16x8 bf = __builtin_bit_cast(bf16x8, bu);
          acc[ct2] =
              __builtin_amdgcn_mfma_f32_16x16x32_bf16(bf, afr[kk4], acc[ct2], 0, 0, 0);
        }
      }
      if (r < N) {
        unsigned short* Prow = Pout + (size_t)r * D;
#pragma unroll
        for (int ct2 = 0; ct2 < 4; ct2++) {
          int colb = half * 64 + ct2 * 16 + quad * 4;
          float4 bi = *(const float4*)(&B[colb]);
          unsigned int lo = ((unsigned int)f2bf(acc[ct2][1] + bi.y) << 16) |
                            f2bf(acc[ct2][0] + bi.x);
          unsigned int hi = ((unsigned int)f2bf(acc[ct2][3] + bi.w) << 16) |
                            f2bf(acc[ct2][2] + bi.z);
          uint2 pk; pk.x = lo; pk.y = hi;
          *(uint2*)(&Prow[colb]) = pk;
        }
      }
    }
  }
}

// unordered CSR segment assignment: one wave handles 64 nodes, one atomicAdd
__device__ __forceinline__ void assign_chunk(
    int a, const int* __restrict__ counts, int* __restrict__ row_start,
    int* __restrict__ cursor, int* __restrict__ allocg, int N, int lane)
{
  int n = a * 64 + lane;
  int cnt = (n < N) ? counts[n] : 0;
  int x = cnt;
#pragma unroll
  for (int off = 1; off < 64; off <<= 1) {
    int y = __shfl_up(x, off, 64);
    if (lane >= off) x += y;
  }
  int wtot = __shfl(x, 63, 64);
  int wbase = 0;
  if (lane == 63) wbase = atomicAdd(allocg, wtot);
  wbase = __shfl(wbase, 63, 64);
  if (n < N) { int v = wbase + x - cnt; row_start[n] = v; cursor[n] = v; }
}

// one dst node per wave — round-8 body verbatim (r4-proven; fb_node is
// fetch-traffic-bound at ~2.2TB/s random-gather ceiling — r6/r7 falsified
// occupancy and VMEM-count theories; keep this body untouched).
__device__ __forceinline__ void edge_vals(
    const unsigned short* __restrict__ P, size_t Nsz, int s, int h,
    const uint4 (&qa)[3][2], const uint4 (&qw)[3][2],
    float (&av)[3], float (&lv)[3])
{
#pragma unroll
  for (int m = 0; m < 3; m++) {
    const unsigned short* kp = P + ((size_t)m * Nsz + s) * 128 + h * 16;
    uint4 k0 = *(const uint4*)kp, k1 = *(const uint4*)(kp + 8);
    const unsigned int* ka = (const unsigned int*)&k0;
    const unsigned int* kb = (const unsigned int*)&k1;
    const unsigned int* a0 = (const unsigned int*)&qa[m][0];
    const unsigned int* a1 = (const unsigned int*)&qa[m][1];
    const unsigned int* w0 = (const unsigned int*)&qw[m][0];
    const unsigned int* w1 = (const unsigned int*)&qw[m][1];
    float da = 0.f, dw = 0.f;
#pragma unroll
    for (int j = 0; j < 4; j++) {
      acc2(ka[j], a0[j], da); acc2(kb[j], a1[j], da);
      acc2(ka[j], w0[j], dw); acc2(kb[j], w1[j], dw);
    }
    av[m] = da;
    lv[m] = dw;
  }
  float mx = fmaxf(lv[0], fmaxf(lv[1], lv[2]));
  float e0 = __expf(lv[0] - mx), e1 = __expf(lv[1] - mx), e2 = __expf(lv[2] - mx);
  float inv = 1.f / (e0 + e1 + e2);
  lv[0] = e0 * inv; lv[1] = e1 * inv; lv[2] = e2 * inv;
}

__device__ __forceinline__ void node_one(
    int n, const unsigned short* __restrict__ P,
    const int* __restrict__ row_start, const int* __restrict__ counts,
    const int* __restrict__ srcs, unsigned short* __restrict__ hagg,
    int N, int lane)
{
  int ro = row_start[n];
  int deg = counts[n];
  float acc00 = 0, acc01 = 0, acc10 = 0, acc11 = 0, acc20 = 0, acc21 = 0;
  if (deg > 0) {
    int h = lane & 7, slot = lane >> 3;
    size_t Nsz = (size_t)N;
    uint4 qa[3][2], qw[3][2];
#pragma unroll
    for (int m = 0; m < 3; m++) {
      const unsigned short* qap = P + ((size_t)(3 + m) * Nsz + n) * 128 + h * 16;
      const unsigned short* qwp = P + ((size_t)(6 + m) * Nsz + n) * 128 + h * 16;
      qa[m][0] = *(const uint4*)qap; qa[m][1] = *(const uint4*)(qap + 8);
      qw[m][0] = *(const uint4*)qwp; qw[m][1] = *(const uint4*)(qwp + 8);
    }
    int nch = (deg + 7) >> 3;
    float cX0[4] = {}, cX1[4] = {}, cX2[4] = {}, cEa[4] = {}, cT[4] = {};
    int cS[4] = {};
    float sA0 = 0, sA1 = 0, sA2 = 0, sAl = 0;
#pragma unroll
    for (int c = 0; c < 4; c++) {
      int idx = c * 8 + slot;
      if (c < nch && idx < deg) {
        int s = srcs[ro + idx]; cS[c] = s;
        float av[3], lv[3];
        edge_vals(P, Nsz, s, h, qa, qw, av, lv);
        float e0 = __expf(av[0]), e1 = __expf(av[1]), e2 = __expf(av[2]);
        float align = -(fabsf(av[0]-av[1]) + fabsf(av[0]-av[2]) + fabsf(av[1]-av[2])) * (1.f/3.f);
        float ea = __expf(align);
        cX0[c] = lv[0] * e0; cX1[c] = lv[1] * e1; cX2[c] = lv[2] * e2; cEa[c] = ea;
        sA0 += e0; sA1 += e1; sA2 += e2; sAl += ea;
      }
    }
    for (int c = 4; c < nch; c++) {
      int idx = c * 8 + slot;
      if (idx < deg) {
        int s = srcs[ro + idx];
        float av[3], lv[3];
        edge_vals(P, Nsz, s, h, qa, qw, av, lv);
        float align = -(fabsf(av[0]-av[1]) + fabsf(av[0]-av[2]) + fabsf(av[1]-av[2])) * (1.f/3.f);
        sA0 += __expf(av[0]); sA1 += __expf(av[1]); sA2 += __expf(av[2]);
        sAl += __expf(align);
      }
    }
#pragma unroll
    for (int off = 8; off < 64; off <<= 1) {
      sA0 += __shfl_xor(sA0, off, 64);
      sA1 += __shfl_xor(sA1, off, 64);
      sA2 += __shfl_xor(sA2, off, 64);
      sAl += __shfl_xor(sAl, off, 64);
    }
    float rA0 = 1.f / fmaxf(sA0, 1e-30f), rA1 = 1.f / fmaxf(sA1, 1e-30f);
    float rA2 = 1.f / fmaxf(sA2, 1e-30f), rAl = 1.f / fmaxf(sAl, 1e-30f);
    float sT = 0;
#pragma unroll
    for (int c = 0; c < 4; c++) {
      int idx = c * 8 + slot;
      if (c < nch && idx < deg) {
        float t = (cX0[c] * rA0 + cX1[c] * rA1 + cX2[c] * rA2) * (cEa[c] * rAl);
        cT[c] = t;
        sT += __expf(t);
      }
    }
    for (int c = 4; c < nch; c++) {
      int idx = c * 8 + slot;
      if (idx < deg) {
        int s = srcs[ro + idx];
        float av[3], lv[3];
        edge_vals(P, Nsz, s, h, qa, qw, av, lv);
        float align = -(fabsf(av[0]-av[1]) + fabsf(av[0]-av[2]) + fabsf(av[1]-av[2])) * (1.f/3.f);
        float t = (lv[0]*__expf(av[0])*rA0 + lv[1]*__expf(av[1])*rA1 + lv[2]*__expf(av[2])*rA2)
                  * (__expf(align) * rAl);
        sT += __expf(t);
      }
    }
#pragma unroll
    for (int off = 8; off < 64; off <<= 1) sT += __shfl_xor(sT, off, 64);
    float rT = 1.f / fmaxf(sT, 1e-30f);
    const unsigned int* Pu = (const unsigned int*)P;
    int hl = lane >> 3;
#pragma unroll
    for (int c = 0; c < 4; c++) {
      if (c < nch) {
        int idx = c * 8 + slot;
        float beta = (idx < deg) ? __expf(cT[c]) * rT : 0.f;
        int sv = cS[c];
        float bj[8]; int sj[8];
#pragma unroll
        for (int jj = 0; jj < 8; jj++) {
          bj[jj] = __shfl(beta, jj * 8 + hl, 64);
          sj[jj] = __shfl(sv, jj * 8, 64);
        }
#pragma unroll
        for (int jj = 0; jj < 8; jj++) {
          size_t base9 = ((size_t)9 * Nsz + sj[jj]) * 64 + lane;
          unsigned int u0 = Pu[base9];
          unsigned int u1 = Pu[base9 + Nsz * 64];
          unsigned int u2 = Pu[base9 + 2 * Nsz * 64];
          float b = bj[jj];
          acc00 += b * bf2f((unsigned short)u0); acc01 += b * bf2f((unsigned short)(u0 >> 16));
          acc10 += b * bf2f((unsigned short)u1); acc11 += b * bf2f((unsigned short)(u1 >> 16));
          acc20 += b * bf2f((unsigned short)u2); acc21 += b * bf2f((unsigned short)(u2 >> 16));
        }
      }
    }
    for (int c = 4; c < nch; c++) {
      int idx = c * 8 + slot;
      float beta = 0.f; int sv = 0;
      if (idx < deg) {
        sv = srcs[ro + idx];
        float av[3], lv[3];
        edge_vals(P, Nsz, sv, h, qa, qw, av, lv);
        float align = -(fabsf(av[0]-av[1]) + fabsf(av[0]-av[2]) + fabsf(av[1]-av[2])) * (1.f/3.f);
        float t = (lv[0]*__expf(av[0])*rA0 + lv[1]*__expf(av[1])*rA1 + lv[2]*__expf(av[2])*rA2)
                  * (__expf(align) * rAl);
        beta = __expf(t) * rT;
      }
      int jmax = min(8, deg - c * 8);
      for (int jj = 0; jj < jmax; jj++) {
        float b = __shfl(beta, jj * 8 + hl, 64);
        int s = __shfl(sv, jj * 8, 64);
        size_t base9 = ((size_t)9 * Nsz + s) * 64 + lane;
        unsigned int u0 = Pu[base9];
        unsigned int u1 = Pu[base9 + Nsz * 64];
        unsigned int u2 = Pu[base9 + 2 * Nsz * 64];
        acc00 += b * bf2f((unsigned short)u0); acc01 += b * bf2f((unsigned short)(u0 >> 16));
        acc10 += b * bf2f((unsigned short)u1); acc11 += b * bf2f((unsigned short)(u1 >> 16));
        acc20 += b * bf2f((unsigned short)u2); acc21 += b * bf2f((unsigned short)(u2 >> 16));
      }
    }
  }
  unsigned int* ho = (unsigned int*)hagg;
  ho[((size_t)0 * N + n) * 64 + lane] = ((unsigned int)f2bf(acc01) << 16) | f2bf(acc00);
  ho[((size_t)1 * N + n) * 64 + lane] = ((unsigned int)f2bf(acc11) << 16) | f2bf(acc10);
  ho[((size_t)2 * N + n) * 64 + lane] = ((unsigned int)f2bf(acc21) << 16) | f2bf(acc20);
}

// one 64-row output tile for ONE 64-column half; Wa half pre-staged in Wt.
// r8: swapped MFMA (see proj_tile) -> lane owns 4 consecutive out cols for
// row row0+l16: float4 X loads + float4 out stores (was 16+16 scalar f32).
__device__ __forceinline__ void out_tile_half(
    int t, int half, const unsigned short* __restrict__ Hagg,
    const float* __restrict__ ba,
    const float* __restrict__ x0, const float* __restrict__ x1,
    const float* __restrict__ x2, float alpha,
    float* __restrict__ out, int N, const unsigned short* Wt, int tid)
{
  int m = t % 3, rt = t / 3;
  const float* X = (m == 0) ? x0 : ((m == 1) ? x1 : x2);
  float oma = 1.f - alpha;
  int wave = tid >> 6, lane = tid & 63;
  int quad = lane >> 4, l16 = lane & 15;
  int row0 = rt * 64 + wave * 16;
  int arow = row0 + l16; if (arow >= N) arow = N - 1;
  const unsigned short* hp = Hagg + ((size_t)m * N + arow) * D;
  floatx4 acc[4];
#pragma unroll
  for (int ct = 0; ct < 4; ct++) acc[ct] = (floatx4)0.f;
#pragma unroll
  for (int kk = 0; kk < 128; kk += 32) {
    uint4 au = *(const uint4*)(hp + kk + quad * 8);
    bf16x8 af = __builtin_bit_cast(bf16x8, au);
#pragma unroll
    for (int ct = 0; ct < 4; ct++) {
      uint4 bu = *(const uint4*)(&Wt[(ct * 16 + l16) * 136 + kk + quad * 8]);
      bf16x8 bf = __builtin_bit_cast(bf16x8, bu);
      acc[ct] = __builtin_amdgcn_mfma_f32_16x16x32_bf16(bf, af, acc[ct], 0, 0, 0);
    }
  }
  int r = row0 + l16;
  if (r < N) {
    float* om = out + (size_t)m * N * D + (size_t)r * D;
    const float* xr = X + (size_t)r * D;
#pragma unroll
    for (int ct = 0; ct < 4; ct++) {
      int colb = half * 64 + ct * 16 + quad * 4;
      float4 bi = *(const float4*)(&ba[colb]);
      float4 xv = *(const float4*)(&xr[colb]);
      float4 res;
      res.x = (acc[ct][0] + bi.x) * alpha + xv.x * oma;
      res.y = (acc[ct][1] + bi.y) * alpha + xv.y * oma;
      res.z = (acc[ct][2] + bi.z) * alpha + xv.z * oma;
      res.w = (acc[ct][3] + bi.w) * alpha + xv.w * oma;
      *(float4*)(&om[colb]) = res;
    }
  }
}

// =============== multi-kernel path (primary) ================================
__global__ __launch_bounds__(256) void fb_misc(
    const float* Wk, const float* bk, const float* Wq, const float* bq,
    const float* Wv, const float* bv,
    const float* rel_att, const float* rel_msg, const float* rel_pri,
    const float* wm0, const float* wm1, const float* wm2,
    unsigned short* Wt_all, float* bias_all,
    const int* dst, int* counts, int E)
{
  int b = blockIdx.x;
  if (b < 384) {
    int g = b * 256 + threadIdx.x;
    if (g < 6 * 16384)
      fold_item(g, Wk, bk, Wq, bq, Wv, bv, rel_att, rel_msg, rel_pri,
                wm0, wm1, wm2, Wt_all, bias_all);
  } else {
    int e = (b - 384) * 256 + threadIdx.x;
    if (e < E) atomicAdd(&counts[dst[e]], 1);
  }
}

__global__ __launch_bounds__(256) void fb_projassign(
    const float* x0, const float* x1, const float* x2,
    const unsigned short* Wt_all, const float* bias_all,
    unsigned short* P, const int* counts, int* row_start, int* cursor,
    int* allocg, int N)
{
  __shared__ __attribute__((aligned(16))) unsigned short Wt[64 * 136];
  int ntiles = ((N + 63) / 64) * 3;
  int b = blockIdx.x;
  if (b < ntiles) {
    proj_tile(b, x0, x1, x2, Wt_all, bias_all, P, N, Wt, threadIdx.x);
  } else {
    int a = (b - ntiles) * 4 + (threadIdx.x >> 6);
    if (a < (N + 63) / 64)
      assign_chunk(a, counts, row_start, cursor, allocg, N, threadIdx.x & 63);
  }
}

__global__ void fb_scatter(const int* dst, const int* src, int* cursor,
                           int* src_sorted, int E) {
  int e = blockIdx.x * 256 + threadIdx.x;
  if (e < E) {
    int d = dst[e];
    int pos = atomicAdd(&cursor[d], 1);
    src_sorted[pos] = src[e];
  }
}

__global__ __launch_bounds__(256) void fb_node(
    const unsigned short* P, const int* row_start, const int* counts,
    const int* srcs, unsigned short* hagg, int N)
{
  int n = blockIdx.x * 4 + (threadIdx.x >> 6);
  if (n < N) node_one(n, P, row_start, counts, srcs, hagg, N, threadIdx.x & 63);
}

__global__ __launch_bounds__(256) void fb_out(
    const unsigned short* Hagg, const float* Wa, const float* ba,
    const float* x0, const float* x1, const float* x2, const float* skip,
    float* out, int N)
{
  __shared__ __attribute__((aligned(16))) unsigned short Wt[64 * 136];
  int tid = threadIdx.x;
  float alpha = 1.f / (1.f + __expf(-skip[0]));
  for (int half = 0; half < 2; half++) {
    __syncthreads();
#pragma unroll
    for (int it = 0; it < 8; it++) {
      int idx = it * 256 + tid;
      int k = idx >> 4;
      int c4 = (idx & 15) << 2;
      float4 w = *(const float4*)(&Wa[k * 128 + half * 64 + c4]);
      Wt[(c4 + 0) * 136 + k] = f2bf(w.x);
      Wt[(c4 + 1) * 136 + k] = f2bf(w.y);
      Wt[(c4 + 2) * 136 + k] = f2bf(w.z);
      Wt[(c4 + 3) * 136 + k] = f2bf(w.w);
    }
    __syncthreads();
    out_tile_half(blockIdx.x, half, Hagg, ba, x0, x1, x2, alpha, out, N, Wt, tid);
  }
}

// ---------------------------------------------------------------- launch
extern "C" void kernel_launch(void* const* d_in, const int* in_sizes, int n_in,
                              void* d_out, int out_size, void* d_ws, size_t ws_size,
                              hipStream_t stream) {
  const float* x0 = (const float*)d_in[0];
  const float* x1 = (const float*)d_in[1];
  const float* x2 = (const float*)d_in[2];
  const float* Wk = (const float*)d_in[3];
  const float* bk = (const float*)d_in[4];
  const float* Wq = (const float*)d_in[5];
  const float* bq = (const float*)d_in[6];
  const float* Wv = (const float*)d_in[7];
  const float* bv = (const float*)d_in[8];
  const float* Wa = (const float*)d_in[9];
  const float* ba = (const float*)d_in[10];
  const float* rel_att = (const float*)d_in[11];
  const float* rel_msg = (const float*)d_in[12];
  const float* rel_pri = (const float*)d_in[13];
  const float* wm0 = (const float*)d_in[14];
  const float* wm1 = (const float*)d_in[15];
  const float* wm2 = (const float*)d_in[16];
  const float* skip = (const float*)d_in[17];
  const int* src = (const int*)d_in[18];
  const int* dstv = (const int*)d_in[19];
  int N = in_sizes[0] / D;      // 20000
  int E = in_sizes[18];         // 160000

  char* wsb = (char*)d_ws;
  size_t off = 0;
  auto alloc_b = [&](size_t bytes) { size_t o = off; off += (bytes + 63) & ~(size_t)63; return o; };
  unsigned short* P         = (unsigned short*)(wsb + alloc_b((size_t)12 * N * D * 2));
  unsigned short* Wt_all    = (unsigned short*)(wsb + alloc_b((size_t)6 * 16384 * 2));
  float*          bias_all  = (float*)(wsb + alloc_b((size_t)6 * 128 * 4));
  // ctrl: bar[8*16] | alloc[16] | counts[N] | cursor[N]
  int*            ctrl      = (int*)(wsb + alloc_b(((size_t)144 + 2 * N) * 4));
  int*            row_start = (int*)(wsb + alloc_b((size_t)(N + 1) * 4));
  int*            src_sorted= (int*)(wsb + alloc_b((size_t)E * 4));
  unsigned short* hagg      = (unsigned short*)(wsb + alloc_b((size_t)3 * N * D * 2));
  int* allocg = ctrl + 128;
  int* counts = ctrl + 144;
  int* cursor = ctrl + 144 + N;

  // zero alloc + counts (cursor written by assign phase)
  hipMemsetAsync(ctrl, 0, ((size_t)144 + N) * sizeof(int), stream);

  int ntiles = ((N + 63) / 64) * 3;
  int nchunks = (N + 63) / 64;
  fb_misc<<<dim3(384 + (E + 255) / 256), 256, 0, stream>>>(
      Wk, bk, Wq, bq, Wv, bv, rel_att, rel_msg, rel_pri, wm0, wm1, wm2,
      Wt_all, bias_all, dstv, counts, E);
  fb_projassign<<<dim3(ntiles + (nchunks + 3) / 4), 256, 0, stream>>>(
      x0, x1, x2, Wt_all, bias_all, P, counts, row_start, cursor, allocg, N);
  fb_scatter<<<dim3((E + 255) / 256), 256, 0, stream>>>(
      dstv, src, cursor, src_sorted, E);
  fb_node<<<dim3((N + 3) / 4), 256, 0, stream>>>(
      P, row_start, counts, src_sorted, hagg, N);
  fb_out<<<dim3(ntiles), 256, 0, stream>>>(
      hagg, Wa, ba, x0, x1, x2, skip, (float*)d_out, N);
}

// Round 9
// 241.946 us; speedup vs baseline: 1.6520x; 1.0040x over previous
//
#include <hip/hip_runtime.h>

#define D 128
#define NH 8

typedef __bf16 bf16x8 __attribute__((ext_vector_type(8)));
typedef unsigned short ushortx8 __attribute__((ext_vector_type(8)));
typedef float floatx4 __attribute__((ext_vector_type(4)));

__device__ __forceinline__ float bf2f(unsigned short u) {
  union { unsigned int i; float f; } x; x.i = ((unsigned int)u) << 16; return x.f;
}
__device__ __forceinline__ unsigned short f2bf(float f) {
  union { float f; unsigned int i; } x; x.f = f;
  unsigned int i = x.i;
  return (unsigned short)((i + 0x7FFFu + ((i >> 16) & 1u)) >> 16);
}
__device__ __forceinline__ void acc2(unsigned int ku, unsigned int qu, float& s) {
  union { unsigned int i; float f; } a, b;
  a.i = ku << 16;          b.i = qu << 16;          s += a.f * b.f;
  a.i = ku & 0xffff0000u;  b.i = qu & 0xffff0000u;  s += a.f * b.f;
}

// =============== phase helpers (proven bodies) ==============================
// weight fold: p0 Wk ; p1 Wq.rel_attT * pri*2.5 ; p2..4 Wq.wm_mT ; p5 Wv.rel_msg
__device__ __forceinline__ void fold_item(
    int gid,
    const float* __restrict__ Wk, const float* __restrict__ bk,
    const float* __restrict__ Wq, const float* __restrict__ bq,
    const float* __restrict__ Wv, const float* __restrict__ bv,
    const float* __restrict__ rel_att, const float* __restrict__ rel_msg,
    const float* __restrict__ rel_pri,
    const float* __restrict__ wm0, const float* __restrict__ wm1,
    const float* __restrict__ wm2,
    unsigned short* __restrict__ Wt_all, float* __restrict__ bias_all)
{
  int p = gid >> 14;
  int idx = gid & 16383;
  int c = idx >> 7, k = idx & 127;
  int h = c >> 4, r = c & 15;
  float wsum = 0.f, bsum = 0.f;
  if (p == 0) {
    wsum = Wk[k * 128 + c];
    bsum = bk[c];
  } else if (p <= 4) {
    const float* M = (p == 1) ? rel_att : ((p == 2) ? wm0 : ((p == 3) ? wm1 : wm2));
#pragma unroll
    for (int f = 0; f < 16; f++) {
      float mv = M[h * 256 + r * 16 + f];
      wsum += Wq[k * 128 + h * 16 + f] * mv;
      bsum += bq[h * 16 + f] * mv;
    }
    if (p == 1) { float sc = rel_pri[h] * 2.5f; wsum *= sc; bsum *= sc; }
  } else {
#pragma unroll
    for (int d = 0; d < 16; d++) {
      float mv = rel_msg[h * 256 + d * 16 + r];
      wsum += Wv[k * 128 + h * 16 + d] * mv;
      bsum += bv[h * 16 + d] * mv;
    }
  }
  Wt_all[(size_t)p * 16384 + c * 128 + k] = f2bf(wsum);
  if (k == 0) bias_all[p * 128 + c] = bsum;
}

// one 64-row x 4-plane projection tile, 256 threads.
// r9: FULL-WIDTH weight staging (128x136 = 34.8KB LDS; standalone kernel,
// HW packs blocks — the half-panel was a mega-kernel-API relic). 4 stagings
// + 8 barriers per tile (was 8 + 16). Swapped MFMA (r8) retained: lane owns
// P[row0+l16][ct2*16+quad*4 ..+3] -> dwordx2 stores.
__device__ __forceinline__ void proj_tile(
    int t, const float* __restrict__ x0, const float* __restrict__ x1,
    const float* __restrict__ x2,
    const unsigned short* __restrict__ Wt_all, const float* __restrict__ bias_all,
    unsigned short* __restrict__ P, int N, unsigned short* Wt, int tid)
{
  int m = t % 3, rt = t / 3;
  const float* X = (m == 0) ? x0 : ((m == 1) ? x1 : x2);
  int wave = tid >> 6, lane = tid & 63;
  int quad = lane >> 4, l16 = lane & 15;
  int row0 = rt * 64 + wave * 16;
  int arow = row0 + l16; if (arow >= N) arow = N - 1;
  const float* ap = X + (size_t)arow * D;
  bf16x8 afr[4];
#pragma unroll
  for (int kk4 = 0; kk4 < 4; kk4++) {
    float4 f0 = *(const float4*)(ap + kk4 * 32 + quad * 8);
    float4 f1 = *(const float4*)(ap + kk4 * 32 + quad * 8 + 4);
    ushortx8 uu;
    uu[0]=f2bf(f0.x); uu[1]=f2bf(f0.y); uu[2]=f2bf(f0.z); uu[3]=f2bf(f0.w);
    uu[4]=f2bf(f1.x); uu[5]=f2bf(f1.y); uu[6]=f2bf(f1.z); uu[7]=f2bf(f1.w);
    afr[kk4] = __builtin_bit_cast(bf16x8, uu);
  }
  int r = row0 + l16;                       // this lane's output row (swapped)
  for (int pt = 0; pt < 4; pt++) {
    int wp = (pt == 0) ? 0 : ((pt == 1) ? 1 : ((pt == 2) ? (2 + m) : 5));
    const unsigned short* Wsrc = Wt_all + (size_t)wp * 16384;
    const float* B = bias_all + wp * 128;
    unsigned short* Pout = P + (size_t)(pt * 3 + m) * N * D;
    __syncthreads();
#pragma unroll
    for (int it = 0; it < 8; it++) {
      int idx = it * 256 + tid;              // 0..2047
      int c = idx >> 4, kc = (idx & 15) << 3;
      *(uint4*)(&Wt[c * 136 + kc]) = *(const uint4*)(&Wsrc[c * 128 + kc]);
    }
    __syncthreads();
    floatx4 acc[8];
#pragma unroll
    for (int ct = 0; ct < 8; ct++) acc[ct] = (floatx4)0.f;
#pragma unroll
    for (int kk4 = 0; kk4 < 4; kk4++) {
#pragma unroll
      for (int ct2 = 0; ct2 < 8; ct2++) {
        uint4 bu = *(const uint4*)(&Wt[(ct2 * 16 + l16) * 136 + kk4 * 32 + quad * 8]);
        bf16x8 bf = __builtin_bit_cast(bf16x8, bu);
        acc[ct2] =
            __builtin_amdgcn_mfma_f32_16x16x32_bf16(bf, afr[kk4], acc[ct2], 0, 0, 0);
      }
    }
    if (r < N) {
      unsigned short* Prow = Pout + (size_t)r * D;
#pragma unroll
      for (int ct2 = 0; ct2 < 8; ct2++) {
        int colb = ct2 * 16 + quad * 4;
        float4 bi = *(const float4*)(&B[colb]);
        unsigned int lo = ((unsigned int)f2bf(acc[ct2][1] + bi.y) << 16) |
                          f2bf(acc[ct2][0] + bi.x);
        unsigned int hi = ((unsigned int)f2bf(acc[ct2][3] + bi.w) << 16) |
                          f2bf(acc[ct2][2] + bi.z);
        uint2 pk; pk.x = lo; pk.y = hi;
        *(uint2*)(&Prow[colb]) = pk;
      }
    }
  }
}

// unordered CSR segment assignment: one wave handles 64 nodes, one atomicAdd
__device__ __forceinline__ void assign_chunk(
    int a, const int* __restrict__ counts, int* __restrict__ row_start,
    int* __restrict__ cursor, int* __restrict__ allocg, int N, int lane)
{
  int n = a * 64 + lane;
  int cnt = (n < N) ? counts[n] : 0;
  int x = cnt;
#pragma unroll
  for (int off = 1; off < 64; off <<= 1) {
    int y = __shfl_up(x, off, 64);
    if (lane >= off) x += y;
  }
  int wtot = __shfl(x, 63, 64);
  int wbase = 0;
  if (lane == 63) wbase = atomicAdd(allocg, wtot);
  wbase = __shfl(wbase, 63, 64);
  if (n < N) { int v = wbase + x - cnt; row_start[n] = v; cursor[n] = v; }
}

// one dst node per wave — r4-proven body; fb_node is fetch-traffic-bound at
// ~2.2TB/s random-gather ceiling (r6/r7 falsified occupancy and VMEM-count
// theories). Untouched.
__device__ __forceinline__ void edge_vals(
    const unsigned short* __restrict__ P, size_t Nsz, int s, int h,
    const uint4 (&qa)[3][2], const uint4 (&qw)[3][2],
    float (&av)[3], float (&lv)[3])
{
#pragma unroll
  for (int m = 0; m < 3; m++) {
    const unsigned short* kp = P + ((size_t)m * Nsz + s) * 128 + h * 16;
    uint4 k0 = *(const uint4*)kp, k1 = *(const uint4*)(kp + 8);
    const unsigned int* ka = (const unsigned int*)&k0;
    const unsigned int* kb = (const unsigned int*)&k1;
    const unsigned int* a0 = (const unsigned int*)&qa[m][0];
    const unsigned int* a1 = (const unsigned int*)&qa[m][1];
    const unsigned int* w0 = (const unsigned int*)&qw[m][0];
    const unsigned int* w1 = (const unsigned int*)&qw[m][1];
    float da = 0.f, dw = 0.f;
#pragma unroll
    for (int j = 0; j < 4; j++) {
      acc2(ka[j], a0[j], da); acc2(kb[j], a1[j], da);
      acc2(ka[j], w0[j], dw); acc2(kb[j], w1[j], dw);
    }
    av[m] = da;
    lv[m] = dw;
  }
  float mx = fmaxf(lv[0], fmaxf(lv[1], lv[2]));
  float e0 = __expf(lv[0] - mx), e1 = __expf(lv[1] - mx), e2 = __expf(lv[2] - mx);
  float inv = 1.f / (e0 + e1 + e2);
  lv[0] = e0 * inv; lv[1] = e1 * inv; lv[2] = e2 * inv;
}

__device__ __forceinline__ void node_one(
    int n, const unsigned short* __restrict__ P,
    const int* __restrict__ row_start, const int* __restrict__ counts,
    const int* __restrict__ srcs, unsigned short* __restrict__ hagg,
    int N, int lane)
{
  int ro = row_start[n];
  int deg = counts[n];
  float acc00 = 0, acc01 = 0, acc10 = 0, acc11 = 0, acc20 = 0, acc21 = 0;
  if (deg > 0) {
    int h = lane & 7, slot = lane >> 3;
    size_t Nsz = (size_t)N;
    uint4 qa[3][2], qw[3][2];
#pragma unroll
    for (int m = 0; m < 3; m++) {
      const unsigned short* qap = P + ((size_t)(3 + m) * Nsz + n) * 128 + h * 16;
      const unsigned short* qwp = P + ((size_t)(6 + m) * Nsz + n) * 128 + h * 16;
      qa[m][0] = *(const uint4*)qap; qa[m][1] = *(const uint4*)(qap + 8);
      qw[m][0] = *(const uint4*)qwp; qw[m][1] = *(const uint4*)(qwp + 8);
    }
    int nch = (deg + 7) >> 3;
    float cX0[4] = {}, cX1[4] = {}, cX2[4] = {}, cEa[4] = {}, cT[4] = {};
    int cS[4] = {};
    float sA0 = 0, sA1 = 0, sA2 = 0, sAl = 0;
#pragma unroll
    for (int c = 0; c < 4; c++) {
      int idx = c * 8 + slot;
      if (c < nch && idx < deg) {
        int s = srcs[ro + idx]; cS[c] = s;
        float av[3], lv[3];
        edge_vals(P, Nsz, s, h, qa, qw, av, lv);
        float e0 = __expf(av[0]), e1 = __expf(av[1]), e2 = __expf(av[2]);
        float align = -(fabsf(av[0]-av[1]) + fabsf(av[0]-av[2]) + fabsf(av[1]-av[2])) * (1.f/3.f);
        float ea = __expf(align);
        cX0[c] = lv[0] * e0; cX1[c] = lv[1] * e1; cX2[c] = lv[2] * e2; cEa[c] = ea;
        sA0 += e0; sA1 += e1; sA2 += e2; sAl += ea;
      }
    }
    for (int c = 4; c < nch; c++) {
      int idx = c * 8 + slot;
      if (idx < deg) {
        int s = srcs[ro + idx];
        float av[3], lv[3];
        edge_vals(P, Nsz, s, h, qa, qw, av, lv);
        float align = -(fabsf(av[0]-av[1]) + fabsf(av[0]-av[2]) + fabsf(av[1]-av[2])) * (1.f/3.f);
        sA0 += __expf(av[0]); sA1 += __expf(av[1]); sA2 += __expf(av[2]);
        sAl += __expf(align);
      }
    }
#pragma unroll
    for (int off = 8; off < 64; off <<= 1) {
      sA0 += __shfl_xor(sA0, off, 64);
      sA1 += __shfl_xor(sA1, off, 64);
      sA2 += __shfl_xor(sA2, off, 64);
      sAl += __shfl_xor(sAl, off, 64);
    }
    float rA0 = 1.f / fmaxf(sA0, 1e-30f), rA1 = 1.f / fmaxf(sA1, 1e-30f);
    float rA2 = 1.f / fmaxf(sA2, 1e-30f), rAl = 1.f / fmaxf(sAl, 1e-30f);
    float sT = 0;
#pragma unroll
    for (int c = 0; c < 4; c++) {
      int idx = c * 8 + slot;
      if (c < nch && idx < deg) {
        float t = (cX0[c] * rA0 + cX1[c] * rA1 + cX2[c] * rA2) * (cEa[c] * rAl);
        cT[c] = t;
        sT += __expf(t);
      }
    }
    for (int c = 4; c < nch; c++) {
      int idx = c * 8 + slot;
      if (idx < deg) {
        int s = srcs[ro + idx];
        float av[3], lv[3];
        edge_vals(P, Nsz, s, h, qa, qw, av, lv);
        float align = -(fabsf(av[0]-av[1]) + fabsf(av[0]-av[2]) + fabsf(av[1]-av[2])) * (1.f/3.f);
        float t = (lv[0]*__expf(av[0])*rA0 + lv[1]*__expf(av[1])*rA1 + lv[2]*__expf(av[2])*rA2)
                  * (__expf(align) * rAl);
        sT += __expf(t);
      }
    }
#pragma unroll
    for (int off = 8; off < 64; off <<= 1) sT += __shfl_xor(sT, off, 64);
    float rT = 1.f / fmaxf(sT, 1e-30f);
    const unsigned int* Pu = (const unsigned int*)P;
    int hl = lane >> 3;
#pragma unroll
    for (int c = 0; c < 4; c++) {
      if (c < nch) {
        int idx = c * 8 + slot;
        float beta = (idx < deg) ? __expf(cT[c]) * rT : 0.f;
        int sv = cS[c];
        float bj[8]; int sj[8];
#pragma unroll
        for (int jj = 0; jj < 8; jj++) {
          bj[jj] = __shfl(beta, jj * 8 + hl, 64);
          sj[jj] = __shfl(sv, jj * 8, 64);
        }
#pragma unroll
        for (int jj = 0; jj < 8; jj++) {
          size_t base9 = ((size_t)9 * Nsz + sj[jj]) * 64 + lane;
          unsigned int u0 = Pu[base9];
          unsigned int u1 = Pu[base9 + Nsz * 64];
          unsigned int u2 = Pu[base9 + 2 * Nsz * 64];
          float b = bj[jj];
          acc00 += b * bf2f((unsigned short)u0); acc01 += b * bf2f((unsigned short)(u0 >> 16));
          acc10 += b * bf2f((unsigned short)u1); acc11 += b * bf2f((unsigned short)(u1 >> 16));
          acc20 += b * bf2f((unsigned short)u2); acc21 += b * bf2f((unsigned short)(u2 >> 16));
        }
      }
    }
    for (int c = 4; c < nch; c++) {
      int idx = c * 8 + slot;
      float beta = 0.f; int sv = 0;
      if (idx < deg) {
        sv = srcs[ro + idx];
        float av[3], lv[3];
        edge_vals(P, Nsz, sv, h, qa, qw, av, lv);
        float align = -(fabsf(av[0]-av[1]) + fabsf(av[0]-av[2]) + fabsf(av[1]-av[2])) * (1.f/3.f);
        float t = (lv[0]*__expf(av[0])*rA0 + lv[1]*__expf(av[1])*rA1 + lv[2]*__expf(av[2])*rA2)
                  * (__expf(align) * rAl);
        beta = __expf(t) * rT;
      }
      int jmax = min(8, deg - c * 8);
      for (int jj = 0; jj < jmax; jj++) {
        float b = __shfl(beta, jj * 8 + hl, 64);
        int s = __shfl(sv, jj * 8, 64);
        size_t base9 = ((size_t)9 * Nsz + s) * 64 + lane;
        unsigned int u0 = Pu[base9];
        unsigned int u1 = Pu[base9 + Nsz * 64];
        unsigned int u2 = Pu[base9 + 2 * Nsz * 64];
        acc00 += b * bf2f((unsigned short)u0); acc01 += b * bf2f((unsigned short)(u0 >> 16));
        acc10 += b * bf2f((unsigned short)u1); acc11 += b * bf2f((unsigned short)(u1 >> 16));
        acc20 += b * bf2f((unsigned short)u2); acc21 += b * bf2f((unsigned short)(u2 >> 16));
      }
    }
  }
  unsigned int* ho = (unsigned int*)hagg;
  ho[((size_t)0 * N + n) * 64 + lane] = ((unsigned int)f2bf(acc01) << 16) | f2bf(acc00);
  ho[((size_t)1 * N + n) * 64 + lane] = ((unsigned int)f2bf(acc11) << 16) | f2bf(acc10);
  ho[((size_t)2 * N + n) * 64 + lane] = ((unsigned int)f2bf(acc21) << 16) | f2bf(acc20);
}

// one 64-row output tile, FULL width (r9): Wa staged once, hagg row read
// once (was twice with half-panels). Swapped MFMA epilogue: float4 X loads
// + float4 out stores.
__device__ __forceinline__ void out_tile(
    int t, const unsigned short* __restrict__ Hagg,
    const float* __restrict__ ba,
    const float* __restrict__ x0, const float* __restrict__ x1,
    const float* __restrict__ x2, float alpha,
    float* __restrict__ out, int N, const unsigned short* Wt, int tid)
{
  int m = t % 3, rt = t / 3;
  const float* X = (m == 0) ? x0 : ((m == 1) ? x1 : x2);
  float oma = 1.f - alpha;
  int wave = tid >> 6, lane = tid & 63;
  int quad = lane >> 4, l16 = lane & 15;
  int row0 = rt * 64 + wave * 16;
  int arow = row0 + l16; if (arow >= N) arow = N - 1;
  const unsigned short* hp = Hagg + ((size_t)m * N + arow) * D;
  floatx4 acc[8];
#pragma unroll
  for (int ct = 0; ct < 8; ct++) acc[ct] = (floatx4)0.f;
#pragma unroll
  for (int kk = 0; kk < 128; kk += 32) {
    uint4 au = *(const uint4*)(hp + kk + quad * 8);
    bf16x8 af = __builtin_bit_cast(bf16x8, au);
#pragma unroll
    for (int ct = 0; ct < 8; ct++) {
      uint4 bu = *(const uint4*)(&Wt[(ct * 16 + l16) * 136 + kk + quad * 8]);
      bf16x8 bf = __builtin_bit_cast(bf16x8, bu);
      acc[ct] = __builtin_amdgcn_mfma_f32_16x16x32_bf16(bf, af, acc[ct], 0, 0, 0);
    }
  }
  int r = row0 + l16;
  if (r < N) {
    float* om = out + (size_t)m * N * D + (size_t)r * D;
    const float* xr = X + (size_t)r * D;
#pragma unroll
    for (int ct = 0; ct < 8; ct++) {
      int colb = ct * 16 + quad * 4;
      float4 bi = *(const float4*)(&ba[colb]);
      float4 xv = *(const float4*)(&xr[colb]);
      float4 res;
      res.x = (acc[ct][0] + bi.x) * alpha + xv.x * oma;
      res.y = (acc[ct][1] + bi.y) * alpha + xv.y * oma;
      res.z = (acc[ct][2] + bi.z) * alpha + xv.z * oma;
      res.w = (acc[ct][3] + bi.w) * alpha + xv.w * oma;
      *(float4*)(&om[colb]) = res;
    }
  }
}

// =============== multi-kernel path (primary) ================================
__global__ __launch_bounds__(256) void fb_misc(
    const float* Wk, const float* bk, const float* Wq, const float* bq,
    const float* Wv, const float* bv,
    const float* rel_att, const float* rel_msg, const float* rel_pri,
    const float* wm0, const float* wm1, const float* wm2,
    unsigned short* Wt_all, float* bias_all,
    const int* dst, int* counts, int E)
{
  int b = blockIdx.x;
  if (b < 384) {
    int g = b * 256 + threadIdx.x;
    if (g < 6 * 16384)
      fold_item(g, Wk, bk, Wq, bq, Wv, bv, rel_att, rel_msg, rel_pri,
                wm0, wm1, wm2, Wt_all, bias_all);
  } else {
    int e = (b - 384) * 256 + threadIdx.x;
    if (e < E) atomicAdd(&counts[dst[e]], 1);
  }
}

__global__ __launch_bounds__(256) void fb_projassign(
    const float* x0, const float* x1, const float* x2,
    const unsigned short* Wt_all, const float* bias_all,
    unsigned short* P, const int* counts, int* row_start, int* cursor,
    int* allocg, int N)
{
  __shared__ __attribute__((aligned(16))) unsigned short Wt[128 * 136];
  int ntiles = ((N + 63) / 64) * 3;
  int b = blockIdx.x;
  if (b < ntiles) {
    proj_tile(b, x0, x1, x2, Wt_all, bias_all, P, N, Wt, threadIdx.x);
  } else {
    int a = (b - ntiles) * 4 + (threadIdx.x >> 6);
    if (a < (N + 63) / 64)
      assign_chunk(a, counts, row_start, cursor, allocg, N, threadIdx.x & 63);
  }
}

__global__ void fb_scatter(const int* dst, const int* src, int* cursor,
                           int* src_sorted, int E) {
  int e = blockIdx.x * 256 + threadIdx.x;
  if (e < E) {
    int d = dst[e];
    int pos = atomicAdd(&cursor[d], 1);
    src_sorted[pos] = src[e];
  }
}

__global__ __launch_bounds__(256) void fb_node(
    const unsigned short* P, const int* row_start, const int* counts,
    const int* srcs, unsigned short* hagg, int N)
{
  int n = blockIdx.x * 4 + (threadIdx.x >> 6);
  if (n < N) node_one(n, P, row_start, counts, srcs, hagg, N, threadIdx.x & 63);
}

__global__ __launch_bounds__(256) void fb_out(
    const unsigned short* Hagg, const float* Wa, const float* ba,
    const float* x0, const float* x1, const float* x2, const float* skip,
    float* out, int N)
{
  __shared__ __attribute__((aligned(16))) unsigned short Wt[128 * 136];
  int tid = threadIdx.x;
#pragma unroll
  for (int it = 0; it < 16; it++) {
    int idx = it * 256 + tid;
    int k = idx >> 5, c4 = (idx & 31) << 2;
    float4 w = *(const float4*)(&Wa[k * 128 + c4]);
    Wt[(c4 + 0) * 136 + k] = f2bf(w.x);
    Wt[(c4 + 1) * 136 + k] = f2bf(w.y);
    Wt[(c4 + 2) * 136 + k] = f2bf(w.z);
    Wt[(c4 + 3) * 136 + k] = f2bf(w.w);
  }
  __syncthreads();
  float alpha = 1.f / (1.f + __expf(-skip[0]));
  out_tile(blockIdx.x, Hagg, ba, x0, x1, x2, alpha, (float*)out, N, Wt, tid);
}

// ---------------------------------------------------------------- launch
extern "C" void kernel_launch(void* const* d_in, const int* in_sizes, int n_in,
                              void* d_out, int out_size, void* d_ws, size_t ws_size,
                              hipStream_t stream) {
  const float* x0 = (const float*)d_in[0];
  const float* x1 = (const float*)d_in[1];
  const float* x2 = (const float*)d_in[2];
  const float* Wk = (const float*)d_in[3];
  const float* bk = (const float*)d_in[4];
  const float* Wq = (const float*)d_in[5];
  const float* bq = (const float*)d_in[6];
  const float* Wv = (const float*)d_in[7];
  const float* bv = (const float*)d_in[8];
  const float* Wa = (const float*)d_in[9];
  const float* ba = (const float*)d_in[10];
  const float* rel_att = (const float*)d_in[11];
  const float* rel_msg = (const float*)d_in[12];
  const float* rel_pri = (const float*)d_in[13];
  const float* wm0 = (const float*)d_in[14];
  const float* wm1 = (const float*)d_in[15];
  const float* wm2 = (const float*)d_in[16];
  const float* skip = (const float*)d_in[17];
  const int* src = (const int*)d_in[18];
  const int* dstv = (const int*)d_in[19];
  int N = in_sizes[0] / D;      // 20000
  int E = in_sizes[18];         // 160000

  char* wsb = (char*)d_ws;
  size_t off = 0;
  auto alloc_b = [&](size_t bytes) { size_t o = off; off += (bytes + 63) & ~(size_t)63; return o; };
  unsigned short* P         = (unsigned short*)(wsb + alloc_b((size_t)12 * N * D * 2));
  unsigned short* Wt_all    = (unsigned short*)(wsb + alloc_b((size_t)6 * 16384 * 2));
  float*          bias_all  = (float*)(wsb + alloc_b((size_t)6 * 128 * 4));
  // ctrl: bar[8*16] | alloc[16] | counts[N] | cursor[N]
  int*            ctrl      = (int*)(wsb + alloc_b(((size_t)144 + 2 * N) * 4));
  int*            row_start = (int*)(wsb + alloc_b((size_t)(N + 1) * 4));
  int*            src_sorted= (int*)(wsb + alloc_b((size_t)E * 4));
  unsigned short* hagg      = (unsigned short*)(wsb + alloc_b((size_t)3 * N * D * 2));
  int* allocg = ctrl + 128;
  int* counts = ctrl + 144;
  int* cursor = ctrl + 144 + N;

  // zero alloc + counts (cursor written by assign phase)
  hipMemsetAsync(ctrl, 0, ((size_t)144 + N) * sizeof(int), stream);

  int ntiles = ((N + 63) / 64) * 3;
  int nchunks = (N + 63) / 64;
  fb_misc<<<dim3(384 + (E + 255) / 256), 256, 0, stream>>>(
      Wk, bk, Wq, bq, Wv, bv, rel_att, rel_msg, rel_pri, wm0, wm1, wm2,
      Wt_all, bias_all, dstv, counts, E);
  fb_projassign<<<dim3(ntiles + (nchunks + 3) / 4), 256, 0, stream>>>(
      x0, x1, x2, Wt_all, bias_all, P, counts, row_start, cursor, allocg, N);
  fb_scatter<<<dim3((E + 255) / 256), 256, 0, stream>>>(
      dstv, src, cursor, src_sorted, E);
  fb_node<<<dim3((N + 3) / 4), 256, 0, stream>>>(
      P, row_start, counts, src_sorted, hagg, N);
  fb_out<<<dim3(ntiles), 256, 0, stream>>>(
      hagg, Wa, ba, x0, x1, x2, skip, (float*)d_out, N);
}

// Round 10
// 233.890 us; speedup vs baseline: 1.7089x; 1.0344x over previous
//
#include <hip/hip_runtime.h>

#define D 128
#define NH 8

typedef __bf16 bf16x8 __attribute__((ext_vector_type(8)));
typedef unsigned short ushortx8 __attribute__((ext_vector_type(8)));
typedef float floatx4 __attribute__((ext_vector_type(4)));

__device__ __forceinline__ float bf2f(unsigned short u) {
  union { unsigned int i; float f; } x; x.i = ((unsigned int)u) << 16; return x.f;
}
__device__ __forceinline__ unsigned short f2bf(float f) {
  union { float f; unsigned int i; } x; x.f = f;
  unsigned int i = x.i;
  return (unsigned short)((i + 0x7FFFu + ((i >> 16) & 1u)) >> 16);
}
__device__ __forceinline__ void acc2(unsigned int ku, unsigned int qu, float& s) {
  union { unsigned int i; float f; } a, b;
  a.i = ku << 16;          b.i = qu << 16;          s += a.f * b.f;
  a.i = ku & 0xffff0000u;  b.i = qu & 0xffff0000u;  s += a.f * b.f;
}

// =============== phase helpers (proven bodies) ==============================
// weight fold: p0 Wk ; p1 Wq.rel_attT * pri*2.5 ; p2..4 Wq.wm_mT ; p5 Wv.rel_msg
// r10: p6 = Wa transposed to bf16 [col][k] (consumed by the fused node+out
// kernel's per-block staging — avoids 5000x f32->bf16 conversion).
__device__ __forceinline__ void fold_item(
    int gid,
    const float* __restrict__ Wk, const float* __restrict__ bk,
    const float* __restrict__ Wq, const float* __restrict__ bq,
    const float* __restrict__ Wv, const float* __restrict__ bv,
    const float* __restrict__ Wa,
    const float* __restrict__ rel_att, const float* __restrict__ rel_msg,
    const float* __restrict__ rel_pri,
    const float* __restrict__ wm0, const float* __restrict__ wm1,
    const float* __restrict__ wm2,
    unsigned short* __restrict__ Wt_all, float* __restrict__ bias_all)
{
  int p = gid >> 14;
  int idx = gid & 16383;
  int c = idx >> 7, k = idx & 127;
  int h = c >> 4, r = c & 15;
  float wsum = 0.f, bsum = 0.f;
  if (p == 0) {
    wsum = Wk[k * 128 + c];
    bsum = bk[c];
  } else if (p <= 4) {
    const float* M = (p == 1) ? rel_att : ((p == 2) ? wm0 : ((p == 3) ? wm1 : wm2));
#pragma unroll
    for (int f = 0; f < 16; f++) {
      float mv = M[h * 256 + r * 16 + f];
      wsum += Wq[k * 128 + h * 16 + f] * mv;
      bsum += bq[h * 16 + f] * mv;
    }
    if (p == 1) { float sc = rel_pri[h] * 2.5f; wsum *= sc; bsum *= sc; }
  } else if (p == 5) {
#pragma unroll
    for (int d = 0; d < 16; d++) {
      float mv = rel_msg[h * 256 + d * 16 + r];
      wsum += Wv[k * 128 + h * 16 + d] * mv;
      bsum += bv[h * 16 + d] * mv;
    }
  } else {            // p == 6: Wa^T bf16
    wsum = Wa[k * 128 + c];
    bsum = 0.f;
  }
  Wt_all[(size_t)p * 16384 + c * 128 + k] = f2bf(wsum);
  if (k == 0) bias_all[p * 128 + c] = bsum;
}

// one 64-row x 4-plane projection tile, 256 threads. Full-width staging
// (r9) + swapped MFMA epilogue (r8): lane owns P[row0+l16][ct2*16+quad*4..+3]
// -> dwordx2 stores.
__device__ __forceinline__ void proj_tile(
    int t, const float* __restrict__ x0, const float* __restrict__ x1,
    const float* __restrict__ x2,
    const unsigned short* __restrict__ Wt_all, const float* __restrict__ bias_all,
    unsigned short* __restrict__ P, int N, unsigned short* Wt, int tid)
{
  int m = t % 3, rt = t / 3;
  const float* X = (m == 0) ? x0 : ((m == 1) ? x1 : x2);
  int wave = tid >> 6, lane = tid & 63;
  int quad = lane >> 4, l16 = lane & 15;
  int row0 = rt * 64 + wave * 16;
  int arow = row0 + l16; if (arow >= N) arow = N - 1;
  const float* ap = X + (size_t)arow * D;
  bf16x8 afr[4];
#pragma unroll
  for (int kk4 = 0; kk4 < 4; kk4++) {
    float4 f0 = *(const float4*)(ap + kk4 * 32 + quad * 8);
    float4 f1 = *(const float4*)(ap + kk4 * 32 + quad * 8 + 4);
    ushortx8 uu;
    uu[0]=f2bf(f0.x); uu[1]=f2bf(f0.y); uu[2]=f2bf(f0.z); uu[3]=f2bf(f0.w);
    uu[4]=f2bf(f1.x); uu[5]=f2bf(f1.y); uu[6]=f2bf(f1.z); uu[7]=f2bf(f1.w);
    afr[kk4] = __builtin_bit_cast(bf16x8, uu);
  }
  int r = row0 + l16;                       // this lane's output row (swapped)
  for (int pt = 0; pt < 4; pt++) {
    int wp = (pt == 0) ? 0 : ((pt == 1) ? 1 : ((pt == 2) ? (2 + m) : 5));
    const unsigned short* Wsrc = Wt_all + (size_t)wp * 16384;
    const float* B = bias_all + wp * 128;
    unsigned short* Pout = P + (size_t)(pt * 3 + m) * N * D;
    __syncthreads();
#pragma unroll
    for (int it = 0; it < 8; it++) {
      int idx = it * 256 + tid;              // 0..2047
      int c = idx >> 4, kc = (idx & 15) << 3;
      *(uint4*)(&Wt[c * 136 + kc]) = *(const uint4*)(&Wsrc[c * 128 + kc]);
    }
    __syncthreads();
    floatx4 acc[8];
#pragma unroll
    for (int ct = 0; ct < 8; ct++) acc[ct] = (floatx4)0.f;
#pragma unroll
    for (int kk4 = 0; kk4 < 4; kk4++) {
#pragma unroll
      for (int ct2 = 0; ct2 < 8; ct2++) {
        uint4 bu = *(const uint4*)(&Wt[(ct2 * 16 + l16) * 136 + kk4 * 32 + quad * 8]);
        bf16x8 bf = __builtin_bit_cast(bf16x8, bu);
        acc[ct2] =
            __builtin_amdgcn_mfma_f32_16x16x32_bf16(bf, afr[kk4], acc[ct2], 0, 0, 0);
      }
    }
    if (r < N) {
      unsigned short* Prow = Pout + (size_t)r * D;
#pragma unroll
      for (int ct2 = 0; ct2 < 8; ct2++) {
        int colb = ct2 * 16 + quad * 4;
        float4 bi = *(const float4*)(&B[colb]);
        unsigned int lo = ((unsigned int)f2bf(acc[ct2][1] + bi.y) << 16) |
                          f2bf(acc[ct2][0] + bi.x);
        unsigned int hi = ((unsigned int)f2bf(acc[ct2][3] + bi.w) << 16) |
                          f2bf(acc[ct2][2] + bi.z);
        uint2 pk; pk.x = lo; pk.y = hi;
        *(uint2*)(&Prow[colb]) = pk;
      }
    }
  }
}

// unordered CSR segment assignment: one wave handles 64 nodes, one atomicAdd
__device__ __forceinline__ void assign_chunk(
    int a, const int* __restrict__ counts, int* __restrict__ row_start,
    int* __restrict__ cursor, int* __restrict__ allocg, int N, int lane)
{
  int n = a * 64 + lane;
  int cnt = (n < N) ? counts[n] : 0;
  int x = cnt;
#pragma unroll
  for (int off = 1; off < 64; off <<= 1) {
    int y = __shfl_up(x, off, 64);
    if (lane >= off) x += y;
  }
  int wtot = __shfl(x, 63, 64);
  int wbase = 0;
  if (lane == 63) wbase = atomicAdd(allocg, wtot);
  wbase = __shfl(wbase, 63, 64);
  if (n < N) { int v = wbase + x - cnt; row_start[n] = v; cursor[n] = v; }
}

// one dst node per wave — r4-proven body; fb_node is fetch-traffic-bound at
// ~2.2TB/s random-gather ceiling (r6/r7 falsified occupancy and VMEM-count
// theories). r10: results go to the block's LDS Hs tile instead of global
// hagg (row = m*4 + wave, 136-ushort row pitch).
__device__ __forceinline__ void edge_vals(
    const unsigned short* __restrict__ P, size_t Nsz, int s, int h,
    const uint4 (&qa)[3][2], const uint4 (&qw)[3][2],
    float (&av)[3], float (&lv)[3])
{
#pragma unroll
  for (int m = 0; m < 3; m++) {
    const unsigned short* kp = P + ((size_t)m * Nsz + s) * 128 + h * 16;
    uint4 k0 = *(const uint4*)kp, k1 = *(const uint4*)(kp + 8);
    const unsigned int* ka = (const unsigned int*)&k0;
    const unsigned int* kb = (const unsigned int*)&k1;
    const unsigned int* a0 = (const unsigned int*)&qa[m][0];
    const unsigned int* a1 = (const unsigned int*)&qa[m][1];
    const unsigned int* w0 = (const unsigned int*)&qw[m][0];
    const unsigned int* w1 = (const unsigned int*)&qw[m][1];
    float da = 0.f, dw = 0.f;
#pragma unroll
    for (int j = 0; j < 4; j++) {
      acc2(ka[j], a0[j], da); acc2(kb[j], a1[j], da);
      acc2(ka[j], w0[j], dw); acc2(kb[j], w1[j], dw);
    }
    av[m] = da;
    lv[m] = dw;
  }
  float mx = fmaxf(lv[0], fmaxf(lv[1], lv[2]));
  float e0 = __expf(lv[0] - mx), e1 = __expf(lv[1] - mx), e2 = __expf(lv[2] - mx);
  float inv = 1.f / (e0 + e1 + e2);
  lv[0] = e0 * inv; lv[1] = e1 * inv; lv[2] = e2 * inv;
}

__device__ __forceinline__ void node_one(
    int n, const unsigned short* __restrict__ P,
    const int* __restrict__ row_start, const int* __restrict__ counts,
    const int* __restrict__ srcs, unsigned short* __restrict__ Hs,
    int N, int lane, int wave)
{
  int ro = row_start[n];
  int deg = counts[n];
  float acc00 = 0, acc01 = 0, acc10 = 0, acc11 = 0, acc20 = 0, acc21 = 0;
  if (deg > 0) {
    int h = lane & 7, slot = lane >> 3;
    size_t Nsz = (size_t)N;
    uint4 qa[3][2], qw[3][2];
#pragma unroll
    for (int m = 0; m < 3; m++) {
      const unsigned short* qap = P + ((size_t)(3 + m) * Nsz + n) * 128 + h * 16;
      const unsigned short* qwp = P + ((size_t)(6 + m) * Nsz + n) * 128 + h * 16;
      qa[m][0] = *(const uint4*)qap; qa[m][1] = *(const uint4*)(qap + 8);
      qw[m][0] = *(const uint4*)qwp; qw[m][1] = *(const uint4*)(qwp + 8);
    }
    int nch = (deg + 7) >> 3;
    float cX0[4] = {}, cX1[4] = {}, cX2[4] = {}, cEa[4] = {}, cT[4] = {};
    int cS[4] = {};
    float sA0 = 0, sA1 = 0, sA2 = 0, sAl = 0;
#pragma unroll
    for (int c = 0; c < 4; c++) {
      int idx = c * 8 + slot;
      if (c < nch && idx < deg) {
        int s = srcs[ro + idx]; cS[c] = s;
        float av[3], lv[3];
        edge_vals(P, Nsz, s, h, qa, qw, av, lv);
        float e0 = __expf(av[0]), e1 = __expf(av[1]), e2 = __expf(av[2]);
        float align = -(fabsf(av[0]-av[1]) + fabsf(av[0]-av[2]) + fabsf(av[1]-av[2])) * (1.f/3.f);
        float ea = __expf(align);
        cX0[c] = lv[0] * e0; cX1[c] = lv[1] * e1; cX2[c] = lv[2] * e2; cEa[c] = ea;
        sA0 += e0; sA1 += e1; sA2 += e2; sAl += ea;
      }
    }
    for (int c = 4; c < nch; c++) {
      int idx = c * 8 + slot;
      if (idx < deg) {
        int s = srcs[ro + idx];
        float av[3], lv[3];
        edge_vals(P, Nsz, s, h, qa, qw, av, lv);
        float align = -(fabsf(av[0]-av[1]) + fabsf(av[0]-av[2]) + fabsf(av[1]-av[2])) * (1.f/3.f);
        sA0 += __expf(av[0]); sA1 += __expf(av[1]); sA2 += __expf(av[2]);
        sAl += __expf(align);
      }
    }
#pragma unroll
    for (int off = 8; off < 64; off <<= 1) {
      sA0 += __shfl_xor(sA0, off, 64);
      sA1 += __shfl_xor(sA1, off, 64);
      sA2 += __shfl_xor(sA2, off, 64);
      sAl += __shfl_xor(sAl, off, 64);
    }
    float rA0 = 1.f / fmaxf(sA0, 1e-30f), rA1 = 1.f / fmaxf(sA1, 1e-30f);
    float rA2 = 1.f / fmaxf(sA2, 1e-30f), rAl = 1.f / fmaxf(sAl, 1e-30f);
    float sT = 0;
#pragma unroll
    for (int c = 0; c < 4; c++) {
      int idx = c * 8 + slot;
      if (c < nch && idx < deg) {
        float t = (cX0[c] * rA0 + cX1[c] * rA1 + cX2[c] * rA2) * (cEa[c] * rAl);
        cT[c] = t;
        sT += __expf(t);
      }
    }
    for (int c = 4; c < nch; c++) {
      int idx = c * 8 + slot;
      if (idx < deg) {
        int s = srcs[ro + idx];
        float av[3], lv[3];
        edge_vals(P, Nsz, s, h, qa, qw, av, lv);
        float align = -(fabsf(av[0]-av[1]) + fabsf(av[0]-av[2]) + fabsf(av[1]-av[2])) * (1.f/3.f);
        float t = (lv[0]*__expf(av[0])*rA0 + lv[1]*__expf(av[1])*rA1 + lv[2]*__expf(av[2])*rA2)
                  * (__expf(align) * rAl);
        sT += __expf(t);
      }
    }
#pragma unroll
    for (int off = 8; off < 64; off <<= 1) sT += __shfl_xor(sT, off, 64);
    float rT = 1.f / fmaxf(sT, 1e-30f);
    const unsigned int* Pu = (const unsigned int*)P;
    int hl = lane >> 3;
#pragma unroll
    for (int c = 0; c < 4; c++) {
      if (c < nch) {
        int idx = c * 8 + slot;
        float beta = (idx < deg) ? __expf(cT[c]) * rT : 0.f;
        int sv = cS[c];
        float bj[8]; int sj[8];
#pragma unroll
        for (int jj = 0; jj < 8; jj++) {
          bj[jj] = __shfl(beta, jj * 8 + hl, 64);
          sj[jj] = __shfl(sv, jj * 8, 64);
        }
#pragma unroll
        for (int jj = 0; jj < 8; jj++) {
          size_t base9 = ((size_t)9 * Nsz + sj[jj]) * 64 + lane;
          unsigned int u0 = Pu[base9];
          unsigned int u1 = Pu[base9 + Nsz * 64];
          unsigned int u2 = Pu[base9 + 2 * Nsz * 64];
          float b = bj[jj];
          acc00 += b * bf2f((unsigned short)u0); acc01 += b * bf2f((unsigned short)(u0 >> 16));
          acc10 += b * bf2f((unsigned short)u1); acc11 += b * bf2f((unsigned short)(u1 >> 16));
          acc20 += b * bf2f((unsigned short)u2); acc21 += b * bf2f((unsigned short)(u2 >> 16));
        }
      }
    }
    for (int c = 4; c < nch; c++) {
      int idx = c * 8 + slot;
      float beta = 0.f; int sv = 0;
      if (idx < deg) {
        sv = srcs[ro + idx];
        float av[3], lv[3];
        edge_vals(P, Nsz, sv, h, qa, qw, av, lv);
        float align = -(fabsf(av[0]-av[1]) + fabsf(av[0]-av[2]) + fabsf(av[1]-av[2])) * (1.f/3.f);
        float t = (lv[0]*__expf(av[0])*rA0 + lv[1]*__expf(av[1])*rA1 + lv[2]*__expf(av[2])*rA2)
                  * (__expf(align) * rAl);
        beta = __expf(t) * rT;
      }
      int jmax = min(8, deg - c * 8);
      for (int jj = 0; jj < jmax; jj++) {
        float b = __shfl(beta, jj * 8 + hl, 64);
        int s = __shfl(sv, jj * 8, 64);
        size_t base9 = ((size_t)9 * Nsz + s) * 64 + lane;
        unsigned int u0 = Pu[base9];
        unsigned int u1 = Pu[base9 + Nsz * 64];
        unsigned int u2 = Pu[base9 + 2 * Nsz * 64];
        acc00 += b * bf2f((unsigned short)u0); acc01 += b * bf2f((unsigned short)(u0 >> 16));
        acc10 += b * bf2f((unsigned short)u1); acc11 += b * bf2f((unsigned short)(u1 >> 16));
        acc20 += b * bf2f((unsigned short)u2); acc21 += b * bf2f((unsigned short)(u2 >> 16));
      }
    }
  }
  // write this node's 3 hagg rows into the block's LDS tile (row = m*4+wave)
  *(unsigned int*)(&Hs[(0 * 4 + wave) * 136 + 2 * lane]) =
      ((unsigned int)f2bf(acc01) << 16) | f2bf(acc00);
  *(unsigned int*)(&Hs[(1 * 4 + wave) * 136 + 2 * lane]) =
      ((unsigned int)f2bf(acc11) << 16) | f2bf(acc10);
  *(unsigned int*)(&Hs[(2 * 4 + wave) * 136 + 2 * lane]) =
      ((unsigned int)f2bf(acc21) << 16) | f2bf(acc20);
}

// =============== multi-kernel path (primary) ================================
__global__ __launch_bounds__(256) void fb_misc(
    const float* Wk, const float* bk, const float* Wq, const float* bq,
    const float* Wv, const float* bv, const float* Wa,
    const float* rel_att, const float* rel_msg, const float* rel_pri,
    const float* wm0, const float* wm1, const float* wm2,
    unsigned short* Wt_all, float* bias_all,
    const int* dst, int* counts, int E)
{
  int b = blockIdx.x;
  if (b < 448) {
    int g = b * 256 + threadIdx.x;
    if (g < 7 * 16384)
      fold_item(g, Wk, bk, Wq, bq, Wv, bv, Wa, rel_att, rel_msg, rel_pri,
                wm0, wm1, wm2, Wt_all, bias_all);
  } else {
    int e = (b - 448) * 256 + threadIdx.x;
    if (e < E) atomicAdd(&counts[dst[e]], 1);
  }
}

__global__ __launch_bounds__(256) void fb_projassign(
    const float* x0, const float* x1, const float* x2,
    const unsigned short* Wt_all, const float* bias_all,
    unsigned short* P, const int* counts, int* row_start, int* cursor,
    int* allocg, int N)
{
  __shared__ __attribute__((aligned(16))) unsigned short Wt[128 * 136];
  int ntiles = ((N + 63) / 64) * 3;
  int b = blockIdx.x;
  if (b < ntiles) {
    proj_tile(b, x0, x1, x2, Wt_all, bias_all, P, N, Wt, threadIdx.x);
  } else {
    int a = (b - ntiles) * 4 + (threadIdx.x >> 6);
    if (a < (N + 63) / 64)
      assign_chunk(a, counts, row_start, cursor, allocg, N, threadIdx.x & 63);
  }
}

__global__ void fb_scatter(const int* dst, const int* src, int* cursor,
                           int* src_sorted, int E) {
  int e = blockIdx.x * 256 + threadIdx.x;
  if (e < E) {
    int d = dst[e];
    int pos = atomicAdd(&cursor[d], 1);
    src_sorted[pos] = src[e];
  }
}

// r10: fused node attention + output GEMM. Per block: 4 nodes (1/wave).
// Stage Wa^T bf16 (plane 6 of Wt_all) in LDS; node phase writes the 12
// hagg rows (3m x 4 nodes) to an LDS tile; one 16-row MFMA sweep computes
// out = (hagg.Wa + ba)*alpha + x*(1-alpha) with float4 stores. Eliminates
// the 30.7MB hagg global round-trip and the fb_out dispatch.
__global__ __launch_bounds__(256) void fb_node_out(
    const unsigned short* P, const int* row_start, const int* counts,
    const int* srcs, const unsigned short* Wt_all, const float* ba,
    const float* x0, const float* x1, const float* x2, const float* skip,
    float* out, int N)
{
  __shared__ __attribute__((aligned(16))) unsigned short WtS[128 * 136];
  __shared__ __attribute__((aligned(16))) unsigned short Hs[16 * 136];
  int tid = threadIdx.x, wave = tid >> 6, lane = tid & 63;
  // stage Wa^T (bf16, [col][k]) — pure uint4 copies from Wt_all plane 6
  const unsigned short* WaT = Wt_all + (size_t)6 * 16384;
#pragma unroll
  for (int it = 0; it < 8; it++) {
    int idx = it * 256 + tid;
    int c = idx >> 4, kc = (idx & 15) << 3;
    *(uint4*)(&WtS[c * 136 + kc]) = *(const uint4*)(&WaT[c * 128 + kc]);
  }
  // zero pad rows 12..15 of Hs (wave w zeroes row 12+w)
  *(unsigned int*)(&Hs[(12 + wave) * 136 + 2 * lane]) = 0u;

  int n = blockIdx.x * 4 + wave;
  if (n < N)
    node_one(n, P, row_start, counts, srcs, Hs, N, lane, wave);
  else {
    *(unsigned int*)(&Hs[(0 * 4 + wave) * 136 + 2 * lane]) = 0u;
    *(unsigned int*)(&Hs[(1 * 4 + wave) * 136 + 2 * lane]) = 0u;
    *(unsigned int*)(&Hs[(2 * 4 + wave) * 136 + 2 * lane]) = 0u;
  }
  __syncthreads();

  // out GEMM: rows = Hs (16x128, 12 valid), cols = 128; wave w does col
  // tiles ct = 2w, 2w+1. Swapped MFMA: lane(l16,quad) owns row l16,
  // cols ct*16+quad*4..+3.
  int quad = lane >> 4, l16 = lane & 15;
  floatx4 oacc[2];
  oacc[0] = (floatx4)0.f; oacc[1] = (floatx4)0.f;
#pragma unroll
  for (int kk = 0; kk < 128; kk += 32) {
    uint4 au = *(const uint4*)(&Hs[l16 * 136 + kk + quad * 8]);
    bf16x8 af = __builtin_bit_cast(bf16x8, au);
#pragma unroll
    for (int j = 0; j < 2; j++) {
      int ct = wave * 2 + j;
      uint4 bu = *(const uint4*)(&WtS[(ct * 16 + l16) * 136 + kk + quad * 8]);
      bf16x8 bf = __builtin_bit_cast(bf16x8, bu);
      oacc[j] = __builtin_amdgcn_mfma_f32_16x16x32_bf16(bf, af, oacc[j], 0, 0, 0);
    }
  }
  if (l16 < 12) {
    int m = l16 >> 2, wsrc = l16 & 3;
    int n_out = blockIdx.x * 4 + wsrc;
    if (n_out < N) {
      float alpha = 1.f / (1.f + __expf(-skip[0]));
      float oma = 1.f - alpha;
      const float* X = (m == 0) ? x0 : ((m == 1) ? x1 : x2);
      const float* xr = X + (size_t)n_out * D;
      float* om = out + (size_t)m * N * D + (size_t)n_out * D;
#pragma unroll
      for (int j = 0; j < 2; j++) {
        int colb = (wave * 2 + j) * 16 + quad * 4;
        float4 bi = *(const float4*)(&ba[colb]);
        float4 xv = *(const float4*)(&xr[colb]);
        float4 res;
        res.x = (oacc[j][0] + bi.x) * alpha + xv.x * oma;
        res.y = (oacc[j][1] + bi.y) * alpha + xv.y * oma;
        res.z = (oacc[j][2] + bi.z) * alpha + xv.z * oma;
        res.w = (oacc[j][3] + bi.w) * alpha + xv.w * oma;
        *(float4*)(&om[colb]) = res;
      }
    }
  }
}

// ---------------------------------------------------------------- launch
extern "C" void kernel_launch(void* const* d_in, const int* in_sizes, int n_in,
                              void* d_out, int out_size, void* d_ws, size_t ws_size,
                              hipStream_t stream) {
  const float* x0 = (const float*)d_in[0];
  const float* x1 = (const float*)d_in[1];
  const float* x2 = (const float*)d_in[2];
  const float* Wk = (const float*)d_in[3];
  const float* bk = (const float*)d_in[4];
  const float* Wq = (const float*)d_in[5];
  const float* bq = (const float*)d_in[6];
  const float* Wv = (const float*)d_in[7];
  const float* bv = (const float*)d_in[8];
  const float* Wa = (const float*)d_in[9];
  const float* ba = (const float*)d_in[10];
  const float* rel_att = (const float*)d_in[11];
  const float* rel_msg = (const float*)d_in[12];
  const float* rel_pri = (const float*)d_in[13];
  const float* wm0 = (const float*)d_in[14];
  const float* wm1 = (const float*)d_in[15];
  const float* wm2 = (const float*)d_in[16];
  const float* skip = (const float*)d_in[17];
  const int* src = (const int*)d_in[18];
  const int* dstv = (const int*)d_in[19];
  int N = in_sizes[0] / D;      // 20000
  int E = in_sizes[18];         // 160000

  char* wsb = (char*)d_ws;
  size_t off = 0;
  auto alloc_b = [&](size_t bytes) { size_t o = off; off += (bytes + 63) & ~(size_t)63; return o; };
  unsigned short* P         = (unsigned short*)(wsb + alloc_b((size_t)12 * N * D * 2));
  unsigned short* Wt_all    = (unsigned short*)(wsb + alloc_b((size_t)7 * 16384 * 2));
  float*          bias_all  = (float*)(wsb + alloc_b((size_t)7 * 128 * 4));
  // ctrl: bar[8*16] | alloc[16] | counts[N] | cursor[N]
  int*            ctrl      = (int*)(wsb + alloc_b(((size_t)144 + 2 * N) * 4));
  int*            row_start = (int*)(wsb + alloc_b((size_t)(N + 1) * 4));
  int*            src_sorted= (int*)(wsb + alloc_b((size_t)E * 4));
  int* allocg = ctrl + 128;
  int* counts = ctrl + 144;
  int* cursor = ctrl + 144 + N;

  // zero alloc + counts (cursor written by assign phase)
  hipMemsetAsync(ctrl, 0, ((size_t)144 + N) * sizeof(int), stream);

  int ntiles = ((N + 63) / 64) * 3;
  int nchunks = (N + 63) / 64;
  fb_misc<<<dim3(448 + (E + 255) / 256), 256, 0, stream>>>(
      Wk, bk, Wq, bq, Wv, bv, Wa, rel_att, rel_msg, rel_pri, wm0, wm1, wm2,
      Wt_all, bias_all, dstv, counts, E);
  fb_projassign<<<dim3(ntiles + (nchunks + 3) / 4), 256, 0, stream>>>(
      x0, x1, x2, Wt_all, bias_all, P, counts, row_start, cursor, allocg, N);
  fb_scatter<<<dim3((E + 255) / 256), 256, 0, stream>>>(
      dstv, src, cursor, src_sorted, E);
  fb_node_out<<<dim3((N + 3) / 4), 256, 0, stream>>>(
      P, row_start, counts, src_sorted, Wt_all, ba, x0, x1, x2, skip,
      (float*)d_out, N);
}

// Round 11
// 224.365 us; speedup vs baseline: 1.7815x; 1.0425x over previous
//
#include <hip/hip_runtime.h>

#define D 128
#define NH 8
#define BCAP 64   // per-node edge bucket capacity (E/N=8, Poisson tail << 64)

typedef __bf16 bf16x8 __attribute__((ext_vector_type(8)));
typedef unsigned short ushortx8 __attribute__((ext_vector_type(8)));
typedef float floatx4 __attribute__((ext_vector_type(4)));

__device__ __forceinline__ float bf2f(unsigned short u) {
  union { unsigned int i; float f; } x; x.i = ((unsigned int)u) << 16; return x.f;
}
__device__ __forceinline__ unsigned short f2bf(float f) {
  union { float f; unsigned int i; } x; x.f = f;
  unsigned int i = x.i;
  return (unsigned short)((i + 0x7FFFu + ((i >> 16) & 1u)) >> 16);
}
__device__ __forceinline__ void acc2(unsigned int ku, unsigned int qu, float& s) {
  union { unsigned int i; float f; } a, b;
  a.i = ku << 16;          b.i = qu << 16;          s += a.f * b.f;
  a.i = ku & 0xffff0000u;  b.i = qu & 0xffff0000u;  s += a.f * b.f;
}

// =============== phase helpers (proven bodies) ==============================
// weight fold: p0 Wk ; p1 Wq.rel_attT * pri*2.5 ; p2..4 Wq.wm_mT ; p5 Wv.rel_msg
// p6 = Wa^T bf16 (consumed by fused node+out staging).
__device__ __forceinline__ void fold_item(
    int gid,
    const float* __restrict__ Wk, const float* __restrict__ bk,
    const float* __restrict__ Wq, const float* __restrict__ bq,
    const float* __restrict__ Wv, const float* __restrict__ bv,
    const float* __restrict__ Wa,
    const float* __restrict__ rel_att, const float* __restrict__ rel_msg,
    const float* __restrict__ rel_pri,
    const float* __restrict__ wm0, const float* __restrict__ wm1,
    const float* __restrict__ wm2,
    unsigned short* __restrict__ Wt_all, float* __restrict__ bias_all)
{
  int p = gid >> 14;
  int idx = gid & 16383;
  int c = idx >> 7, k = idx & 127;
  int h = c >> 4, r = c & 15;
  float wsum = 0.f, bsum = 0.f;
  if (p == 0) {
    wsum = Wk[k * 128 + c];
    bsum = bk[c];
  } else if (p <= 4) {
    const float* M = (p == 1) ? rel_att : ((p == 2) ? wm0 : ((p == 3) ? wm1 : wm2));
#pragma unroll
    for (int f = 0; f < 16; f++) {
      float mv = M[h * 256 + r * 16 + f];
      wsum += Wq[k * 128 + h * 16 + f] * mv;
      bsum += bq[h * 16 + f] * mv;
    }
    if (p == 1) { float sc = rel_pri[h] * 2.5f; wsum *= sc; bsum *= sc; }
  } else if (p == 5) {
#pragma unroll
    for (int d = 0; d < 16; d++) {
      float mv = rel_msg[h * 256 + d * 16 + r];
      wsum += Wv[k * 128 + h * 16 + d] * mv;
      bsum += bv[h * 16 + d] * mv;
    }
  } else {            // p == 6: Wa^T bf16
    wsum = Wa[k * 128 + c];
    bsum = 0.f;
  }
  Wt_all[(size_t)p * 16384 + c * 128 + k] = f2bf(wsum);
  if (k == 0) bias_all[p * 128 + c] = bsum;
}

// one 64-row x 4-plane projection tile, 256 threads. Full-width staging
// (r9) + swapped MFMA epilogue (r8): lane owns P[row0+l16][ct2*16+quad*4..+3]
// -> dwordx2 stores.
__device__ __forceinline__ void proj_tile(
    int t, const float* __restrict__ x0, const float* __restrict__ x1,
    const float* __restrict__ x2,
    const unsigned short* __restrict__ Wt_all, const float* __restrict__ bias_all,
    unsigned short* __restrict__ P, int N, unsigned short* Wt, int tid)
{
  int m = t % 3, rt = t / 3;
  const float* X = (m == 0) ? x0 : ((m == 1) ? x1 : x2);
  int wave = tid >> 6, lane = tid & 63;
  int quad = lane >> 4, l16 = lane & 15;
  int row0 = rt * 64 + wave * 16;
  int arow = row0 + l16; if (arow >= N) arow = N - 1;
  const float* ap = X + (size_t)arow * D;
  bf16x8 afr[4];
#pragma unroll
  for (int kk4 = 0; kk4 < 4; kk4++) {
    float4 f0 = *(const float4*)(ap + kk4 * 32 + quad * 8);
    float4 f1 = *(const float4*)(ap + kk4 * 32 + quad * 8 + 4);
    ushortx8 uu;
    uu[0]=f2bf(f0.x); uu[1]=f2bf(f0.y); uu[2]=f2bf(f0.z); uu[3]=f2bf(f0.w);
    uu[4]=f2bf(f1.x); uu[5]=f2bf(f1.y); uu[6]=f2bf(f1.z); uu[7]=f2bf(f1.w);
    afr[kk4] = __builtin_bit_cast(bf16x8, uu);
  }
  int r = row0 + l16;                       // this lane's output row (swapped)
  for (int pt = 0; pt < 4; pt++) {
    int wp = (pt == 0) ? 0 : ((pt == 1) ? 1 : ((pt == 2) ? (2 + m) : 5));
    const unsigned short* Wsrc = Wt_all + (size_t)wp * 16384;
    const float* B = bias_all + wp * 128;
    unsigned short* Pout = P + (size_t)(pt * 3 + m) * N * D;
    __syncthreads();
#pragma unroll
    for (int it = 0; it < 8; it++) {
      int idx = it * 256 + tid;              // 0..2047
      int c = idx >> 4, kc = (idx & 15) << 3;
      *(uint4*)(&Wt[c * 136 + kc]) = *(const uint4*)(&Wsrc[c * 128 + kc]);
    }
    __syncthreads();
    floatx4 acc[8];
#pragma unroll
    for (int ct = 0; ct < 8; ct++) acc[ct] = (floatx4)0.f;
#pragma unroll
    for (int kk4 = 0; kk4 < 4; kk4++) {
#pragma unroll
      for (int ct2 = 0; ct2 < 8; ct2++) {
        uint4 bu = *(const uint4*)(&Wt[(ct2 * 16 + l16) * 136 + kk4 * 32 + quad * 8]);
        bf16x8 bf = __builtin_bit_cast(bf16x8, bu);
        acc[ct2] =
            __builtin_amdgcn_mfma_f32_16x16x32_bf16(bf, afr[kk4], acc[ct2], 0, 0, 0);
      }
    }
    if (r < N) {
      unsigned short* Prow = Pout + (size_t)r * D;
#pragma unroll
      for (int ct2 = 0; ct2 < 8; ct2++) {
        int colb = ct2 * 16 + quad * 4;
        float4 bi = *(const float4*)(&B[colb]);
        unsigned int lo = ((unsigned int)f2bf(acc[ct2][1] + bi.y) << 16) |
                          f2bf(acc[ct2][0] + bi.x);
        unsigned int hi = ((unsigned int)f2bf(acc[ct2][3] + bi.w) << 16) |
                          f2bf(acc[ct2][2] + bi.z);
        uint2 pk; pk.x = lo; pk.y = hi;
        *(uint2*)(&Prow[colb]) = pk;
      }
    }
  }
}

// one dst node per wave — r4-proven body; fb_node is fetch-traffic-bound at
// ~2.2TB/s random-gather ceiling (r6/r7 falsified occupancy and VMEM-count
// theories). Results go to the block's LDS Hs tile (row = m*4 + wave).
// r11: edges come from the fixed-capacity bucket (srcs = bucket + n*BCAP).
__device__ __forceinline__ void edge_vals(
    const unsigned short* __restrict__ P, size_t Nsz, int s, int h,
    const uint4 (&qa)[3][2], const uint4 (&qw)[3][2],
    float (&av)[3], float (&lv)[3])
{
#pragma unroll
  for (int m = 0; m < 3; m++) {
    const unsigned short* kp = P + ((size_t)m * Nsz + s) * 128 + h * 16;
    uint4 k0 = *(const uint4*)kp, k1 = *(const uint4*)(kp + 8);
    const unsigned int* ka = (const unsigned int*)&k0;
    const unsigned int* kb = (const unsigned int*)&k1;
    const unsigned int* a0 = (const unsigned int*)&qa[m][0];
    const unsigned int* a1 = (const unsigned int*)&qa[m][1];
    const unsigned int* w0 = (const unsigned int*)&qw[m][0];
    const unsigned int* w1 = (const unsigned int*)&qw[m][1];
    float da = 0.f, dw = 0.f;
#pragma unroll
    for (int j = 0; j < 4; j++) {
      acc2(ka[j], a0[j], da); acc2(kb[j], a1[j], da);
      acc2(ka[j], w0[j], dw); acc2(kb[j], w1[j], dw);
    }
    av[m] = da;
    lv[m] = dw;
  }
  float mx = fmaxf(lv[0], fmaxf(lv[1], lv[2]));
  float e0 = __expf(lv[0] - mx), e1 = __expf(lv[1] - mx), e2 = __expf(lv[2] - mx);
  float inv = 1.f / (e0 + e1 + e2);
  lv[0] = e0 * inv; lv[1] = e1 * inv; lv[2] = e2 * inv;
}

__device__ __forceinline__ void node_one(
    int n, const unsigned short* __restrict__ P,
    const int* __restrict__ counts, const int* __restrict__ bucket,
    unsigned short* __restrict__ Hs,
    int N, int lane, int wave)
{
  const int* srcs = bucket + (size_t)n * BCAP;
  int deg = counts[n]; if (deg > BCAP) deg = BCAP;
  float acc00 = 0, acc01 = 0, acc10 = 0, acc11 = 0, acc20 = 0, acc21 = 0;
  if (deg > 0) {
    int h = lane & 7, slot = lane >> 3;
    size_t Nsz = (size_t)N;
    uint4 qa[3][2], qw[3][2];
#pragma unroll
    for (int m = 0; m < 3; m++) {
      const unsigned short* qap = P + ((size_t)(3 + m) * Nsz + n) * 128 + h * 16;
      const unsigned short* qwp = P + ((size_t)(6 + m) * Nsz + n) * 128 + h * 16;
      qa[m][0] = *(const uint4*)qap; qa[m][1] = *(const uint4*)(qap + 8);
      qw[m][0] = *(const uint4*)qwp; qw[m][1] = *(const uint4*)(qwp + 8);
    }
    int nch = (deg + 7) >> 3;
    float cX0[4] = {}, cX1[4] = {}, cX2[4] = {}, cEa[4] = {}, cT[4] = {};
    int cS[4] = {};
    float sA0 = 0, sA1 = 0, sA2 = 0, sAl = 0;
#pragma unroll
    for (int c = 0; c < 4; c++) {
      int idx = c * 8 + slot;
      if (c < nch && idx < deg) {
        int s = srcs[idx]; cS[c] = s;
        float av[3], lv[3];
        edge_vals(P, Nsz, s, h, qa, qw, av, lv);
        float e0 = __expf(av[0]), e1 = __expf(av[1]), e2 = __expf(av[2]);
        float align = -(fabsf(av[0]-av[1]) + fabsf(av[0]-av[2]) + fabsf(av[1]-av[2])) * (1.f/3.f);
        float ea = __expf(align);
        cX0[c] = lv[0] * e0; cX1[c] = lv[1] * e1; cX2[c] = lv[2] * e2; cEa[c] = ea;
        sA0 += e0; sA1 += e1; sA2 += e2; sAl += ea;
      }
    }
    for (int c = 4; c < nch; c++) {
      int idx = c * 8 + slot;
      if (idx < deg) {
        int s = srcs[idx];
        float av[3], lv[3];
        edge_vals(P, Nsz, s, h, qa, qw, av, lv);
        float align = -(fabsf(av[0]-av[1]) + fabsf(av[0]-av[2]) + fabsf(av[1]-av[2])) * (1.f/3.f);
        sA0 += __expf(av[0]); sA1 += __expf(av[1]); sA2 += __expf(av[2]);
        sAl += __expf(align);
      }
    }
#pragma unroll
    for (int off = 8; off < 64; off <<= 1) {
      sA0 += __shfl_xor(sA0, off, 64);
      sA1 += __shfl_xor(sA1, off, 64);
      sA2 += __shfl_xor(sA2, off, 64);
      sAl += __shfl_xor(sAl, off, 64);
    }
    float rA0 = 1.f / fmaxf(sA0, 1e-30f), rA1 = 1.f / fmaxf(sA1, 1e-30f);
    float rA2 = 1.f / fmaxf(sA2, 1e-30f), rAl = 1.f / fmaxf(sAl, 1e-30f);
    float sT = 0;
#pragma unroll
    for (int c = 0; c < 4; c++) {
      int idx = c * 8 + slot;
      if (c < nch && idx < deg) {
        float t = (cX0[c] * rA0 + cX1[c] * rA1 + cX2[c] * rA2) * (cEa[c] * rAl);
        cT[c] = t;
        sT += __expf(t);
      }
    }
    for (int c = 4; c < nch; c++) {
      int idx = c * 8 + slot;
      if (idx < deg) {
        int s = srcs[idx];
        float av[3], lv[3];
        edge_vals(P, Nsz, s, h, qa, qw, av, lv);
        float align = -(fabsf(av[0]-av[1]) + fabsf(av[0]-av[2]) + fabsf(av[1]-av[2])) * (1.f/3.f);
        float t = (lv[0]*__expf(av[0])*rA0 + lv[1]*__expf(av[1])*rA1 + lv[2]*__expf(av[2])*rA2)
                  * (__expf(align) * rAl);
        sT += __expf(t);
      }
    }
#pragma unroll
    for (int off = 8; off < 64; off <<= 1) sT += __shfl_xor(sT, off, 64);
    float rT = 1.f / fmaxf(sT, 1e-30f);
    const unsigned int* Pu = (const unsigned int*)P;
    int hl = lane >> 3;
#pragma unroll
    for (int c = 0; c < 4; c++) {
      if (c < nch) {
        int idx = c * 8 + slot;
        float beta = (idx < deg) ? __expf(cT[c]) * rT : 0.f;
        int sv = cS[c];
        float bj[8]; int sj[8];
#pragma unroll
        for (int jj = 0; jj < 8; jj++) {
          bj[jj] = __shfl(beta, jj * 8 + hl, 64);
          sj[jj] = __shfl(sv, jj * 8, 64);
        }
#pragma unroll
        for (int jj = 0; jj < 8; jj++) {
          size_t base9 = ((size_t)9 * Nsz + sj[jj]) * 64 + lane;
          unsigned int u0 = Pu[base9];
          unsigned int u1 = Pu[base9 + Nsz * 64];
          unsigned int u2 = Pu[base9 + 2 * Nsz * 64];
          float b = bj[jj];
          acc00 += b * bf2f((unsigned short)u0); acc01 += b * bf2f((unsigned short)(u0 >> 16));
          acc10 += b * bf2f((unsigned short)u1); acc11 += b * bf2f((unsigned short)(u1 >> 16));
          acc20 += b * bf2f((unsigned short)u2); acc21 += b * bf2f((unsigned short)(u2 >> 16));
        }
      }
    }
    for (int c = 4; c < nch; c++) {
      int idx = c * 8 + slot;
      float beta = 0.f; int sv = 0;
      if (idx < deg) {
        sv = srcs[idx];
        float av[3], lv[3];
        edge_vals(P, Nsz, sv, h, qa, qw, av, lv);
        float align = -(fabsf(av[0]-av[1]) + fabsf(av[0]-av[2]) + fabsf(av[1]-av[2])) * (1.f/3.f);
        float t = (lv[0]*__expf(av[0])*rA0 + lv[1]*__expf(av[1])*rA1 + lv[2]*__expf(av[2])*rA2)
                  * (__expf(align) * rAl);
        beta = __expf(t) * rT;
      }
      int jmax = min(8, deg - c * 8);
      for (int jj = 0; jj < jmax; jj++) {
        float b = __shfl(beta, jj * 8 + hl, 64);
        int s = __shfl(sv, jj * 8, 64);
        size_t base9 = ((size_t)9 * Nsz + s) * 64 + lane;
        unsigned int u0 = Pu[base9];
        unsigned int u1 = Pu[base9 + Nsz * 64];
        unsigned int u2 = Pu[base9 + 2 * Nsz * 64];
        acc00 += b * bf2f((unsigned short)u0); acc01 += b * bf2f((unsigned short)(u0 >> 16));
        acc10 += b * bf2f((unsigned short)u1); acc11 += b * bf2f((unsigned short)(u1 >> 16));
        acc20 += b * bf2f((unsigned short)u2); acc21 += b * bf2f((unsigned short)(u2 >> 16));
      }
    }
  }
  // write this node's 3 hagg rows into the block's LDS tile (row = m*4+wave)
  *(unsigned int*)(&Hs[(0 * 4 + wave) * 136 + 2 * lane]) =
      ((unsigned int)f2bf(acc01) << 16) | f2bf(acc00);
  *(unsigned int*)(&Hs[(1 * 4 + wave) * 136 + 2 * lane]) =
      ((unsigned int)f2bf(acc11) << 16) | f2bf(acc10);
  *(unsigned int*)(&Hs[(2 * 4 + wave) * 136 + 2 * lane]) =
      ((unsigned int)f2bf(acc21) << 16) | f2bf(acc20);
}

// =============== multi-kernel path (primary) ================================
// r11: CSR prefix-sum/assign/scatter collapsed into ONE bucket-scatter pass
// fused with the fold — the histogram atomicAdd's return value IS the slot.
// Dispatch chain: memset -> misc{fold,bucket-scatter} -> proj -> node_out.
__global__ __launch_bounds__(256) void fb_misc(
    const float* Wk, const float* bk, const float* Wq, const float* bq,
    const float* Wv, const float* bv, const float* Wa,
    const float* rel_att, const float* rel_msg, const float* rel_pri,
    const float* wm0, const float* wm1, const float* wm2,
    unsigned short* Wt_all, float* bias_all,
    const int* dst, const int* src, int* counts, int* bucket, int E)
{
  int b = blockIdx.x;
  if (b < 448) {
    int g = b * 256 + threadIdx.x;
    if (g < 7 * 16384)
      fold_item(g, Wk, bk, Wq, bq, Wv, bv, Wa, rel_att, rel_msg, rel_pri,
                wm0, wm1, wm2, Wt_all, bias_all);
  } else {
    int e = (b - 448) * 256 + threadIdx.x;
    if (e < E) {
      int d = dst[e];
      int pos = atomicAdd(&counts[d], 1);
      bucket[(size_t)d * BCAP + (pos & (BCAP - 1))] = src[e];
    }
  }
}

__global__ __launch_bounds__(256) void fb_proj(
    const float* x0, const float* x1, const float* x2,
    const unsigned short* Wt_all, const float* bias_all,
    unsigned short* P, int N)
{
  __shared__ __attribute__((aligned(16))) unsigned short Wt[128 * 136];
  proj_tile(blockIdx.x, x0, x1, x2, Wt_all, bias_all, P, N, Wt, threadIdx.x);
}

// fused node attention + output GEMM (r10). Per block: 4 nodes (1/wave).
__global__ __launch_bounds__(256) void fb_node_out(
    const unsigned short* P, const int* counts, const int* bucket,
    const unsigned short* Wt_all, const float* ba,
    const float* x0, const float* x1, const float* x2, const float* skip,
    float* out, int N)
{
  __shared__ __attribute__((aligned(16))) unsigned short WtS[128 * 136];
  __shared__ __attribute__((aligned(16))) unsigned short Hs[16 * 136];
  int tid = threadIdx.x, wave = tid >> 6, lane = tid & 63;
  // stage Wa^T (bf16, [col][k]) — pure uint4 copies from Wt_all plane 6
  const unsigned short* WaT = Wt_all + (size_t)6 * 16384;
#pragma unroll
  for (int it = 0; it < 8; it++) {
    int idx = it * 256 + tid;
    int c = idx >> 4, kc = (idx & 15) << 3;
    *(uint4*)(&WtS[c * 136 + kc]) = *(const uint4*)(&WaT[c * 128 + kc]);
  }
  // zero pad rows 12..15 of Hs (wave w zeroes row 12+w)
  *(unsigned int*)(&Hs[(12 + wave) * 136 + 2 * lane]) = 0u;

  int n = blockIdx.x * 4 + wave;
  if (n < N)
    node_one(n, P, counts, bucket, Hs, N, lane, wave);
  else {
    *(unsigned int*)(&Hs[(0 * 4 + wave) * 136 + 2 * lane]) = 0u;
    *(unsigned int*)(&Hs[(1 * 4 + wave) * 136 + 2 * lane]) = 0u;
    *(unsigned int*)(&Hs[(2 * 4 + wave) * 136 + 2 * lane]) = 0u;
  }
  __syncthreads();

  // out GEMM: rows = Hs (16x128, 12 valid), cols = 128; wave w does col
  // tiles ct = 2w, 2w+1. Swapped MFMA: lane(l16,quad) owns row l16,
  // cols ct*16+quad*4..+3.
  int quad = lane >> 4, l16 = lane & 15;
  floatx4 oacc[2];
  oacc[0] = (floatx4)0.f; oacc[1] = (floatx4)0.f;
#pragma unroll
  for (int kk = 0; kk < 128; kk += 32) {
    uint4 au = *(const uint4*)(&Hs[l16 * 136 + kk + quad * 8]);
    bf16x8 af = __builtin_bit_cast(bf16x8, au);
#pragma unroll
    for (int j = 0; j < 2; j++) {
      int ct = wave * 2 + j;
      uint4 bu = *(const uint4*)(&WtS[(ct * 16 + l16) * 136 + kk + quad * 8]);
      bf16x8 bf = __builtin_bit_cast(bf16x8, bu);
      oacc[j] = __builtin_amdgcn_mfma_f32_16x16x32_bf16(bf, af, oacc[j], 0, 0, 0);
    }
  }
  if (l16 < 12) {
    int m = l16 >> 2, wsrc = l16 & 3;
    int n_out = blockIdx.x * 4 + wsrc;
    if (n_out < N) {
      float alpha = 1.f / (1.f + __expf(-skip[0]));
      float oma = 1.f - alpha;
      const float* X = (m == 0) ? x0 : ((m == 1) ? x1 : x2);
      const float* xr = X + (size_t)n_out * D;
      float* om = out + (size_t)m * N * D + (size_t)n_out * D;
#pragma unroll
      for (int j = 0; j < 2; j++) {
        int colb = (wave * 2 + j) * 16 + quad * 4;
        float4 bi = *(const float4*)(&ba[colb]);
        float4 xv = *(const float4*)(&xr[colb]);
        float4 res;
        res.x = (oacc[j][0] + bi.x) * alpha + xv.x * oma;
        res.y = (oacc[j][1] + bi.y) * alpha + xv.y * oma;
        res.z = (oacc[j][2] + bi.z) * alpha + xv.z * oma;
        res.w = (oacc[j][3] + bi.w) * alpha + xv.w * oma;
        *(float4*)(&om[colb]) = res;
      }
    }
  }
}

// ---------------------------------------------------------------- launch
extern "C" void kernel_launch(void* const* d_in, const int* in_sizes, int n_in,
                              void* d_out, int out_size, void* d_ws, size_t ws_size,
                              hipStream_t stream) {
  const float* x0 = (const float*)d_in[0];
  const float* x1 = (const float*)d_in[1];
  const float* x2 = (const float*)d_in[2];
  const float* Wk = (const float*)d_in[3];
  const float* bk = (const float*)d_in[4];
  const float* Wq = (const float*)d_in[5];
  const float* bq = (const float*)d_in[6];
  const float* Wv = (const float*)d_in[7];
  const float* bv = (const float*)d_in[8];
  const float* Wa = (const float*)d_in[9];
  const float* ba = (const float*)d_in[10];
  const float* rel_att = (const float*)d_in[11];
  const float* rel_msg = (const float*)d_in[12];
  const float* rel_pri = (const float*)d_in[13];
  const float* wm0 = (const float*)d_in[14];
  const float* wm1 = (const float*)d_in[15];
  const float* wm2 = (const float*)d_in[16];
  const float* skip = (const float*)d_in[17];
  const int* src = (const int*)d_in[18];
  const int* dstv = (const int*)d_in[19];
  int N = in_sizes[0] / D;      // 20000
  int E = in_sizes[18];         // 160000

  char* wsb = (char*)d_ws;
  size_t off = 0;
  auto alloc_b = [&](size_t bytes) { size_t o = off; off += (bytes + 63) & ~(size_t)63; return o; };
  unsigned short* P         = (unsigned short*)(wsb + alloc_b((size_t)12 * N * D * 2));
  unsigned short* Wt_all    = (unsigned short*)(wsb + alloc_b((size_t)7 * 16384 * 2));
  float*          bias_all  = (float*)(wsb + alloc_b((size_t)7 * 128 * 4));
  // ctrl: pad[144] | counts[N]
  int*            ctrl      = (int*)(wsb + alloc_b(((size_t)144 + N) * 4));
  int*            bucket    = (int*)(wsb + alloc_b((size_t)N * BCAP * 4));
  int* counts = ctrl + 144;

  // zero counts
  hipMemsetAsync(ctrl, 0, ((size_t)144 + N) * sizeof(int), stream);

  int ntiles = ((N + 63) / 64) * 3;
  fb_misc<<<dim3(448 + (E + 255) / 256), 256, 0, stream>>>(
      Wk, bk, Wq, bq, Wv, bv, Wa, rel_att, rel_msg, rel_pri, wm0, wm1, wm2,
      Wt_all, bias_all, dstv, src, counts, bucket, E);
  fb_proj<<<dim3(ntiles), 256, 0, stream>>>(
      x0, x1, x2, Wt_all, bias_all, P, N);
  fb_node_out<<<dim3((N + 3) / 4), 256, 0, stream>>>(
      P, counts, bucket, Wt_all, ba, x0, x1, x2, skip,
      (float*)d_out, N);
}